// Round 5
// baseline (438.260 us; speedup 1.0000x reference)
//
#include <hip/hip_runtime.h>
#include <hip/hip_bf16.h>
#include <cstdint>
#include <cstddef>

#define HD 512
#define BB 64
#define SS 2048
#define VV 32000
#define MM (SS*BB)

typedef __attribute__((ext_vector_type(8))) short bf16x8;
typedef __attribute__((ext_vector_type(4))) float f32x4;

static __device__ __forceinline__ unsigned short f2bf(float f) {
    union { float f; unsigned u; } x; x.f = f;
    unsigned r = x.u + 0x7fffu + ((x.u >> 16) & 1u);
    return (unsigned short)(r >> 16);
}
static __device__ __forceinline__ unsigned pack2(float a, float b) {
    return (unsigned)f2bf(a) | ((unsigned)f2bf(b) << 16);
}
static __device__ __forceinline__ float tanh_fast(float x) {
    float e = __expf(2.f * x);
    return 1.f - 2.f / (e + 1.f);
}
static __device__ __forceinline__ float sigmoid_fast(float x) {
    return 1.f / (1.f + __expf(-x));
}
static __device__ __forceinline__ void gload16(const void* g, void* l) {
    __builtin_amdgcn_global_load_lds(
        (const __attribute__((address_space(1))) void*)g,
        (__attribute__((address_space(3))) void*)l, 16, 0, 0);
}

// ---------------------------------------------------------------------------
// prep: qc[b][n] = hid[b]·Wa[n] + attn_b[n];  WeB = bf16(attn_W[:, H:])
__global__ void prep_kernel(const float* __restrict__ hid,
                            const float* __restrict__ attn_W,
                            const float* __restrict__ attn_b,
                            float* __restrict__ qc,
                            uint4* __restrict__ WeB4) {
    int i = blockIdx.x * 256 + threadIdx.x;      // 0..32767
    int n = i >> 6, b = i & 63;
    const float* hrow = hid + b * HD;
    const float* wrow = attn_W + (size_t)n * (2 * HD);
    float acc = 0.f;
    for (int k = 0; k < HD; k += 4) {
        float4 h4 = *(const float4*)(hrow + k);
        float4 w4 = *(const float4*)(wrow + k);
        acc += h4.x * w4.x + h4.y * w4.y + h4.z * w4.z + h4.w * w4.w;
    }
    qc[b * HD + n] = acc + attn_b[n];
    int col = (i << 3) & 511;
    const float* src = attn_W + (size_t)n * (2 * HD) + HD + col;
    float4 f0 = *(const float4*)(src);
    float4 f1 = *(const float4*)(src + 4);
    uint4 p;
    p.x = pack2(f0.x, f0.y); p.y = pack2(f0.z, f0.w);
    p.z = pack2(f1.x, f1.y); p.w = pack2(f1.z, f1.w);
    WeB4[n * 64 + (col >> 3)] = p;
}

// ---------------------------------------------------------------------------
// scores: BM=64 (one s), BN=512, BK=64, 512 thr. B via gload_lds (L2),
// A register-prefetched 1 iter ahead (HBM latency off critical path).
// Writes scT[b][s] (transposed) for coalesced softmax.
__global__ __launch_bounds__(512, 2) void scores_kernel(
    const float* __restrict__ enc,      // (M, 512) f32, m = s*64+b
    const uint4* __restrict__ WeB4,     // (512 rows x 64 chunks) bf16
    const float* __restrict__ qc,       // (64, 512)
    const float* __restrict__ vvec,     // (512)
    float* __restrict__ scT)            // (B, S)
{
    __shared__ uint4 Ald[64 * 8];       // 8 KB
    __shared__ uint4 Bld[512 * 8];      // 64 KB
    __shared__ float red[64][8];        // 2 KB

    const int tid = threadIdx.x;
    const int wv = tid >> 6, lane = tid & 63, l15 = lane & 15, l4 = lane >> 4;
    const int s_idx = blockIdx.x;
    const int m0 = s_idx * 64;

    f32x4 acc[4][4] = {};

    const int arow = tid >> 3;          // 0..63  (== b)
    const int ac8 = tid & 7;
    const float* aptr = enc + (size_t)(m0 + arow) * HD + ac8 * 8;
    const int aslot = arow * 8 + (ac8 ^ (arow & 7));

    const int brow = wv * 8 + (lane >> 3);
    const int bchunk = (lane & 7) ^ (lane >> 3);
    const char* bg = (const char*)WeB4 + ((size_t)brow * 64 + bchunk) * 16;

    float4 pa[2][2];
    pa[0][0] = *(const float4*)(aptr);
    pa[0][1] = *(const float4*)(aptr + 4);

#pragma unroll
    for (int t = 0; t < 8; ++t) {
        const int cur = t & 1;
        if (t > 0) {
            asm volatile("s_waitcnt lgkmcnt(0)" ::: "memory");
            __builtin_amdgcn_s_barrier();      // prev compute's ds_reads done
        }
        // issue B(t) first (L2-resident), then A(t+1) (HBM) — so the manual
        // vmcnt(2) below waits only on B; A(t+1) stays in flight.
#pragma unroll
        for (int i = 0; i < 8; ++i)
            gload16(bg + (size_t)i * 65536 + t * 128, &Bld[i * 512 + tid]);
        if (t < 7) {
            pa[cur ^ 1][0] = *(const float4*)(aptr + (t + 1) * 64);
            pa[cur ^ 1][1] = *(const float4*)(aptr + (t + 1) * 64 + 4);
        }
        // pack A(t) (regs loaded last iter; auto-waitcnt is already satisfied)
        uint4 u;
        u.x = pack2(pa[cur][0].x, pa[cur][0].y);
        u.y = pack2(pa[cur][0].z, pa[cur][0].w);
        u.z = pack2(pa[cur][1].x, pa[cur][1].y);
        u.w = pack2(pa[cur][1].z, pa[cur][1].w);
        Ald[aslot] = u;
        if (t < 7) { asm volatile("s_waitcnt vmcnt(2) lgkmcnt(0)" ::: "memory"); }
        else       { asm volatile("s_waitcnt vmcnt(0) lgkmcnt(0)" ::: "memory"); }
        __builtin_amdgcn_sched_barrier(0);
        __builtin_amdgcn_s_barrier();
        __builtin_amdgcn_sched_barrier(0);

#pragma unroll
        for (int ks = 0; ks < 2; ++ks) {
            const int chunk = ks * 4 + l4;
            bf16x8 af[4], bfr[4];
#pragma unroll
            for (int mi = 0; mi < 4; ++mi) {
                int row = mi * 16 + l15;
                af[mi] = *(const bf16x8*)&Ald[row * 8 + (chunk ^ (row & 7))];
            }
#pragma unroll
            for (int ni = 0; ni < 4; ++ni) {
                int row = wv * 64 + ni * 16 + l15;
                bfr[ni] = *(const bf16x8*)&Bld[row * 8 + (chunk ^ (row & 7))];
            }
#pragma unroll
            for (int mi = 0; mi < 4; ++mi)
#pragma unroll
                for (int ni = 0; ni < 4; ++ni)
                    acc[mi][ni] = __builtin_amdgcn_mfma_f32_16x16x32_bf16(
                        af[mi], bfr[ni], acc[mi][ni], 0, 0, 0);
        }
    }

    // epilogue: tanh + dot v, reduce across 512 cols
    float vv[4];
#pragma unroll
    for (int ni = 0; ni < 4; ++ni) vv[ni] = vvec[wv * 64 + ni * 16 + l15];
#pragma unroll
    for (int mi = 0; mi < 4; ++mi) {
#pragma unroll
        for (int r = 0; r < 4; ++r) {
            const int rowl = mi * 16 + l4 * 4 + r;   // == b
            float s = 0.f;
#pragma unroll
            for (int ni = 0; ni < 4; ++ni) {
                int n = wv * 64 + ni * 16 + l15;
                float e = acc[mi][ni][r] + qc[rowl * HD + n];
                s += tanh_fast(e) * vv[ni];
            }
#pragma unroll
            for (int msk = 8; msk >= 1; msk >>= 1)
                s += __shfl_xor(s, msk);
            if (l15 == 0) red[rowl][wv] = s;
        }
    }
    __syncthreads();
    if (tid < 64) {
        float t = 0.f;
#pragma unroll
        for (int w = 0; w < 8; ++w) t += red[tid][w];
        scT[(size_t)tid * SS + s_idx] = t;       // transposed
    }
}

// ---------------------------------------------------------------------------
// softmax over s for each b; scT/atT are (B, S) — coalesced row access
__global__ void softmax_kernel(const float* __restrict__ scT,
                               float* __restrict__ atT) {
    const int b = blockIdx.x;
    const int tid = threadIdx.x;  // 256
    __shared__ float sm[256];
    const float* row = scT + (size_t)b * SS;
    float4 v0 = *(const float4*)(row + tid * 8);
    float4 v1 = *(const float4*)(row + tid * 8 + 4);
    float m = fmaxf(fmaxf(fmaxf(v0.x, v0.y), fmaxf(v0.z, v0.w)),
                    fmaxf(fmaxf(v1.x, v1.y), fmaxf(v1.z, v1.w)));
    sm[tid] = m; __syncthreads();
    for (int o = 128; o > 0; o >>= 1) {
        if (tid < o) sm[tid] = fmaxf(sm[tid], sm[tid + o]);
        __syncthreads();
    }
    m = sm[0]; __syncthreads();
    v0.x = __expf(v0.x - m); v0.y = __expf(v0.y - m);
    v0.z = __expf(v0.z - m); v0.w = __expf(v0.w - m);
    v1.x = __expf(v1.x - m); v1.y = __expf(v1.y - m);
    v1.z = __expf(v1.z - m); v1.w = __expf(v1.w - m);
    float sum = (v0.x + v0.y + v0.z + v0.w) + (v1.x + v1.y + v1.z + v1.w);
    sm[tid] = sum; __syncthreads();
    for (int o = 128; o > 0; o >>= 1) {
        if (tid < o) sm[tid] += sm[tid + o];
        __syncthreads();
    }
    float inv = 1.f / sm[0];
    v0.x *= inv; v0.y *= inv; v0.z *= inv; v0.w *= inv;
    v1.x *= inv; v1.y *= inv; v1.z *= inv; v1.w *= inv;
    float* orow = atT + (size_t)b * SS;
    *(float4*)(orow + tid * 8) = v0;
    *(float4*)(orow + tid * 8 + 4) = v1;
}

// ---------------------------------------------------------------------------
// context partials: 64 s-chunks x 64 b blocks, s-chunk = 32, unroll 8
__global__ void ctx_kernel(const float* __restrict__ enc,
                           const float* __restrict__ atT,
                           float* __restrict__ part) {
    const int b = blockIdx.x & 63;
    const int chunk = blockIdx.x >> 6;       // 0..63
    const int h0 = threadIdx.x * 4;          // 128 thr
    float4 a = {0.f, 0.f, 0.f, 0.f};
    const int sbase = chunk * 32;
    const float* wrow = atT + (size_t)b * SS + sbase;
#pragma unroll 8
    for (int si = 0; si < 32; ++si) {
        int s = sbase + si;
        float w = wrow[si];
        float4 e = *(const float4*)(enc + (size_t)(s * BB + b) * HD + h0);
        a.x += w * e.x; a.y += w * e.y; a.z += w * e.z; a.w += w * e.w;
    }
    *(float4*)(part + (size_t)(chunk * BB + b) * HD + h0) = a;
}

__global__ void gather_reduce_kernel(const float* __restrict__ part,
                                     const int* __restrict__ word,
                                     const float* __restrict__ emb,
                                     float* __restrict__ x,
                                     unsigned* __restrict__ y_bf) {
    const int b = blockIdx.x;
    const int h0 = threadIdx.x * 4;          // 128 thr
    float4 a = {0.f, 0.f, 0.f, 0.f};
#pragma unroll 8
    for (int c = 0; c < 64; ++c) {
        float4 p = *(const float4*)(part + (size_t)(c * BB + b) * HD + h0);
        a.x += p.x; a.y += p.y; a.z += p.z; a.w += p.w;
    }
    *(float4*)(x + b * 1024 + HD + h0) = a;
    uint2 u; u.x = pack2(a.x, a.y); u.y = pack2(a.z, a.w);
    *(uint2*)(y_bf + b * 512 + 256 + (h0 >> 1)) = u;
    int w = word[b];
    float4 e = *(const float4*)(emb + (size_t)w * HD + h0);
    *(float4*)(x + b * 1024 + h0) = e;
}

// ---------------------------------------------------------------------------
__global__ void gates_kernel(const float* __restrict__ x,
                             const float* __restrict__ hid,
                             const float* __restrict__ W_ih,
                             const float* __restrict__ W_hh,
                             const float* __restrict__ b_ih,
                             const float* __restrict__ b_hh,
                             float* __restrict__ gi, float* __restrict__ gh) {
    const int tid = threadIdx.x;
    const int b = tid & 63;
    const int j = blockIdx.x * 4 + (tid >> 6);
    float agi = 0.f, agh = 0.f;
    const float* xr = x + b * 1024;
    const float* wr = W_ih + (size_t)j * 1024;
    for (int k = 0; k < 1024; k += 4) {
        float4 xv = *(const float4*)(xr + k);
        float4 w4 = *(const float4*)(wr + k);
        agi += xv.x * w4.x + xv.y * w4.y + xv.z * w4.z + xv.w * w4.w;
    }
    const float* hr = hid + b * HD;
    const float* wh = W_hh + (size_t)j * HD;
    for (int k = 0; k < HD; k += 4) {
        float4 hv = *(const float4*)(hr + k);
        float4 w4 = *(const float4*)(wh + k);
        agh += hv.x * w4.x + hv.y * w4.y + hv.z * w4.z + hv.w * w4.w;
    }
    gi[b * 1536 + j] = agi + b_ih[j];
    gh[b * 1536 + j] = agh + b_hh[j];
}

__global__ void hnew_kernel(const float* __restrict__ gi,
                            const float* __restrict__ gh,
                            const float* __restrict__ hid,
                            float* __restrict__ out_h,
                            unsigned* __restrict__ y_bf) {
    const int b = blockIdx.x;
    const int h = threadIdx.x * 2;           // 256 thr
    float hn[2];
#pragma unroll
    for (int j = 0; j < 2; ++j) {
        int hh = h + j;
        float r = sigmoid_fast(gi[b * 1536 + hh] + gh[b * 1536 + hh]);
        float z = sigmoid_fast(gi[b * 1536 + 512 + hh] + gh[b * 1536 + 512 + hh]);
        float n = tanh_fast(gi[b * 1536 + 1024 + hh] + r * gh[b * 1536 + 1024 + hh]);
        hn[j] = (1.f - z) * n + z * hid[b * HD + hh];
        out_h[b * HD + hh] = hn[j];
    }
    y_bf[b * 512 + (h >> 1)] = pack2(hn[0], hn[1]);
}

// ---------------------------------------------------------------------------
// logits: BM=64, BN=128, BK=64, K=1024 (16 iters), 256 thr (4 waves).
// A from y_bf via gload16 (pre-swizzled source); W f32 reg-prefetch 1-deep.
// grid 250 ~= 1 block/CU, so no occupancy constraint.
__global__ void logits_kernel(
    const unsigned short* __restrict__ y_bf,  // (64, 1024) bf16
    const float* __restrict__ out_W,          // (V, 1024)
    const float* __restrict__ out_b,
    float* __restrict__ logits)               // (64, V)
{
    __shared__ uint4 Yld[64 * 8];      // 8 KB
    __shared__ uint4 Wld[128 * 8];     // 16 KB
    const int tid = threadIdx.x;
    const int wv = tid >> 6, lane = tid & 63, l15 = lane & 15, l4 = lane >> 4;
    const int n0 = blockIdx.x * 128;

    f32x4 acc[4][2] = {};

    // A gload slots: s and s+256; slot s holds global chunk (s&7)^(row&7)
    const int s1 = tid, s2 = tid + 256;
    const int r1 = s1 >> 3, g1 = (s1 & 7) ^ (r1 & 7);
    const int r2 = s2 >> 3, g2 = (s2 & 7) ^ (r2 & 7);
    const unsigned short* ya1 = y_bf + (size_t)r1 * 1024 + g1 * 8;
    const unsigned short* ya2 = y_bf + (size_t)r2 * 1024 + g2 * 8;

    // W: thread covers rows wr+32i (i=0..3) at f32-chunk wc8
    const int wr = tid >> 3, wc8 = tid & 7;
    const int wsl = wc8 ^ (wr & 7);
    const float* wp0 = out_W + (size_t)(n0 + wr) * 1024 + wc8 * 8;

    float4 pw[2][8];
#pragma unroll
    for (int i = 0; i < 4; ++i) {      // W(0)
        pw[0][i * 2]     = *(const float4*)(wp0 + (size_t)i * 32768);
        pw[0][i * 2 + 1] = *(const float4*)(wp0 + (size_t)i * 32768 + 4);
    }

#pragma unroll
    for (int t = 0; t < 16; ++t) {
        const int cur = t & 1;
        if (t > 0) {
            asm volatile("s_waitcnt lgkmcnt(0)" ::: "memory");
            __builtin_amdgcn_s_barrier();
        }
        // A(t) gloads first, then W(t+1) loads — vmcnt(8) waits A only
        gload16(ya1 + t * 64, &Yld[s1]);
        gload16(ya2 + t * 64, &Yld[s2]);
        // pack W(t) -> Wld (auto-wait vmcnt covers pw[cur])
#pragma unroll
        for (int i = 0; i < 4; ++i) {
            uint4 u;
            u.x = pack2(pw[cur][i * 2].x, pw[cur][i * 2].y);
            u.y = pack2(pw[cur][i * 2].z, pw[cur][i * 2].w);
            u.z = pack2(pw[cur][i * 2 + 1].x, pw[cur][i * 2 + 1].y);
            u.w = pack2(pw[cur][i * 2 + 1].z, pw[cur][i * 2 + 1].w);
            Wld[(wr + 32 * i) * 8 + wsl] = u;
        }
        if (t < 15) {
            const int k1 = (t + 1) * 64;
#pragma unroll
            for (int i = 0; i < 4; ++i) {
                pw[cur ^ 1][i * 2]     = *(const float4*)(wp0 + (size_t)i * 32768 + k1);
                pw[cur ^ 1][i * 2 + 1] = *(const float4*)(wp0 + (size_t)i * 32768 + k1 + 4);
            }
            asm volatile("s_waitcnt vmcnt(8) lgkmcnt(0)" ::: "memory");
        } else {
            asm volatile("s_waitcnt vmcnt(0) lgkmcnt(0)" ::: "memory");
        }
        __builtin_amdgcn_sched_barrier(0);
        __builtin_amdgcn_s_barrier();
        __builtin_amdgcn_sched_barrier(0);

#pragma unroll
        for (int ks = 0; ks < 2; ++ks) {
            const int chunk = ks * 4 + l4;
            bf16x8 af[4], bfr[2];
#pragma unroll
            for (int mi = 0; mi < 4; ++mi) {
                int row = mi * 16 + l15;
                af[mi] = *(const bf16x8*)&Yld[row * 8 + (chunk ^ (row & 7))];
            }
#pragma unroll
            for (int ni = 0; ni < 2; ++ni) {
                int row = wv * 32 + ni * 16 + l15;
                bfr[ni] = *(const bf16x8*)&Wld[row * 8 + (chunk ^ (row & 7))];
            }
#pragma unroll
            for (int mi = 0; mi < 4; ++mi)
#pragma unroll
                for (int ni = 0; ni < 2; ++ni)
                    acc[mi][ni] = __builtin_amdgcn_mfma_f32_16x16x32_bf16(
                        af[mi], bfr[ni], acc[mi][ni], 0, 0, 0);
        }
    }
#pragma unroll
    for (int mi = 0; mi < 4; ++mi) {
#pragma unroll
        for (int r = 0; r < 4; ++r) {
            const int b = mi * 16 + l4 * 4 + r;
#pragma unroll
            for (int ni = 0; ni < 2; ++ni) {
                int n = n0 + wv * 32 + ni * 16 + l15;
                logits[(size_t)b * VV + n] = acc[mi][ni][r] + out_b[n];
            }
        }
    }
}

// log_softmax in place over each row of (64, 32000)
__global__ void lsm_kernel(float* __restrict__ logits) {
    const int b = blockIdx.x;
    const int tid = threadIdx.x;  // 1024
    __shared__ float sm[1024];
    float* row = logits + (size_t)b * VV;
    float m = -1e30f;
    for (int i = tid; i < VV; i += 1024) m = fmaxf(m, row[i]);
    sm[tid] = m; __syncthreads();
    for (int o = 512; o > 0; o >>= 1) {
        if (tid < o) sm[tid] = fmaxf(sm[tid], sm[tid + o]);
        __syncthreads();
    }
    m = sm[0]; __syncthreads();
    float s = 0.f;
    for (int i = tid; i < VV; i += 1024) s += __expf(row[i] - m);
    sm[tid] = s; __syncthreads();
    for (int o = 512; o > 0; o >>= 1) {
        if (tid < o) sm[tid] += sm[tid + o];
        __syncthreads();
    }
    float lse = m + __logf(sm[0]);
    for (int i = tid; i < VV; i += 1024) row[i] -= lse;
}

// ---------------------------------------------------------------------------
extern "C" void kernel_launch(void* const* d_in, const int* in_sizes, int n_in,
                              void* d_out, int out_size, void* d_ws, size_t ws_size,
                              hipStream_t stream) {
    (void)in_sizes; (void)n_in; (void)out_size; (void)ws_size;
    const int*   word   = (const int*)d_in[0];
    const float* hid    = (const float*)d_in[1];
    const float* enc    = (const float*)d_in[2];
    const float* emb    = (const float*)d_in[3];
    const float* attn_W = (const float*)d_in[4];
    const float* attn_b = (const float*)d_in[5];
    const float* v      = (const float*)d_in[6];
    const float* W_ih   = (const float*)d_in[7];
    const float* W_hh   = (const float*)d_in[8];
    const float* b_ih   = (const float*)d_in[9];
    const float* b_hh   = (const float*)d_in[10];
    const float* out_W  = (const float*)d_in[11];
    const float* out_b  = (const float*)d_in[12];

    float* out    = (float*)d_out;
    float* logits = out;                         // (B, V)
    float* out_h  = out + (size_t)BB * VV;       // (B, H)

    char* ws = (char*)d_ws;
    float* qc      = (float*)ws;    ws += 64 * 512 * 4;
    uint4* WeB4    = (uint4*)ws;    ws += 512 * 512 * 2;
    float* scT     = (float*)ws;    ws += (size_t)MM * 4;        // (B,S)
    float* atT     = (float*)ws;    ws += (size_t)MM * 4;        // (B,S)
    float* part    = (float*)ws;    ws += (size_t)64 * 64 * 512 * 4;
    float* x       = (float*)ws;    ws += 64 * 1024 * 4;
    unsigned* y_bf = (unsigned*)ws; ws += 64 * 1024 * 2;
    float* gi      = (float*)ws;    ws += 64 * 1536 * 4;
    float* gh      = (float*)ws;    ws += 64 * 1536 * 4;

    prep_kernel<<<128, 256, 0, stream>>>(hid, attn_W, attn_b, qc, WeB4);
    scores_kernel<<<SS, 512, 0, stream>>>(enc, WeB4, qc, v, scT);
    softmax_kernel<<<BB, 256, 0, stream>>>(scT, atT);
    ctx_kernel<<<64 * BB, 128, 0, stream>>>(enc, atT, part);
    gather_reduce_kernel<<<BB, 128, 0, stream>>>(part, word, emb, x, y_bf);
    gates_kernel<<<384, 256, 0, stream>>>(x, hid, W_ih, W_hh, b_ih, b_hh, gi, gh);
    hnew_kernel<<<BB, 256, 0, stream>>>(gi, gh, hid, out_h, y_bf);
    logits_kernel<<<VV / 128, 256, 0, stream>>>((const unsigned short*)y_bf, out_W, out_b, logits);
    lsm_kernel<<<BB, 1024, 0, stream>>>(logits);
}

// Round 6
// 409.371 us; speedup vs baseline: 1.0706x; 1.0706x over previous
//
#include <hip/hip_runtime.h>
#include <hip/hip_bf16.h>
#include <cstdint>
#include <cstddef>

#define HD 512
#define BB 64
#define SS 2048
#define VV 32000
#define MM (SS*BB)

typedef __attribute__((ext_vector_type(8))) short bf16x8;
typedef __attribute__((ext_vector_type(4))) float f32x4;

static __device__ __forceinline__ unsigned short f2bf(float f) {
    union { float f; unsigned u; } x; x.f = f;
    unsigned r = x.u + 0x7fffu + ((x.u >> 16) & 1u);
    return (unsigned short)(r >> 16);
}
static __device__ __forceinline__ unsigned pack2(float a, float b) {
    return (unsigned)f2bf(a) | ((unsigned)f2bf(b) << 16);
}
static __device__ __forceinline__ float bf2f(unsigned short h) {
    union { unsigned u; float f; } x; x.u = ((unsigned)h) << 16; return x.f;
}
static __device__ __forceinline__ float tanh_fast(float x) {
    float e = __expf(2.f * x);
    return 1.f - 2.f / (e + 1.f);
}
static __device__ __forceinline__ float sigmoid_fast(float x) {
    return 1.f / (1.f + __expf(-x));
}
static __device__ __forceinline__ void gload16(const void* g, void* l) {
    __builtin_amdgcn_global_load_lds(
        (const __attribute__((address_space(1))) void*)g,
        (__attribute__((address_space(3))) void*)l, 16, 0, 0);
}

// ---------------------------------------------------------------------------
// prep: qc[b][n] = hid[b]·Wa[n] + attn_b[n];  WeB4 = bf16(attn_W[:, H:])
// stored PRE-SWIZZLED: storage[n][cc] = logical chunk (cc&~7)|((cc&7)^(n&7))
__global__ void prep_kernel(const float* __restrict__ hid,
                            const float* __restrict__ attn_W,
                            const float* __restrict__ attn_b,
                            float* __restrict__ qc,
                            uint4* __restrict__ WeB4) {
    int i = blockIdx.x * 256 + threadIdx.x;      // 0..32767
    int n = i >> 6, b = i & 63;
    const float* hrow = hid + b * HD;
    const float* wrow = attn_W + (size_t)n * (2 * HD);
    float acc = 0.f;
    for (int k = 0; k < HD; k += 4) {
        float4 h4 = *(const float4*)(hrow + k);
        float4 w4 = *(const float4*)(wrow + k);
        acc += h4.x * w4.x + h4.y * w4.y + h4.z * w4.z + h4.w * w4.w;
    }
    qc[b * HD + n] = acc + attn_b[n];
    int col = (i << 3) & 511;                     // logical col base
    int cc0 = col >> 3;                           // logical chunk 0..63
    const float* src = attn_W + (size_t)n * (2 * HD) + HD + col;
    float4 f0 = *(const float4*)(src);
    float4 f1 = *(const float4*)(src + 4);
    uint4 p;
    p.x = pack2(f0.x, f0.y); p.y = pack2(f0.z, f0.w);
    p.z = pack2(f1.x, f1.y); p.w = pack2(f1.z, f1.w);
    int ccs = (cc0 & ~7) | ((cc0 & 7) ^ (n & 7)); // swizzled storage slot
    WeB4[n * 64 + ccs] = p;
}

// ---------------------------------------------------------------------------
// enc -> bf16, pre-swizzled: encB[m][cc] = logical chunk (cc&~7)|((cc&7)^(m&7))
__global__ void enc2bf_kernel(const float* __restrict__ enc,
                              uint4* __restrict__ encB) {
    int idx = blockIdx.x * 2048 + threadIdx.x;
#pragma unroll
    for (int i = 0; i < 8; ++i, idx += 256) {
        int m = idx >> 6, cc = idx & 63;
        int lc = (cc & ~7) | ((cc & 7) ^ (m & 7));
        const float* p = enc + (size_t)m * HD + lc * 8;
        float4 f0 = *(const float4*)p, f1 = *(const float4*)(p + 4);
        uint4 u;
        u.x = pack2(f0.x, f0.y); u.y = pack2(f0.z, f0.w);
        u.z = pack2(f1.x, f1.y); u.w = pack2(f1.z, f1.w);
        encB[idx] = u;
    }
}

// ---------------------------------------------------------------------------
// scores (m97-clone): 256 thr (4 waves, 2m x 2n), BM=128, BN=128, BK=64.
// A and B both bf16 via gload_lds from pre-swizzled storage (linear source).
// grid: bid = nh*1024 + mt  (nh slow => L3 warm pass then 3 L3-hit passes)
__global__ __launch_bounds__(256, 4) void scores_mfma_kernel(
    const uint4* __restrict__ encB,     // (M, 64) chunks
    const uint4* __restrict__ WeB4,     // (512, 64) chunks
    const float* __restrict__ qc,       // (64, 512)
    const float* __restrict__ vvec,     // (512)
    float* __restrict__ scp)            // (M, 4) partials
{
    __shared__ uint4 Ald[1024];         // 16 KB: 128 rows x 8 chunks
    __shared__ uint4 Bld[1024];         // 16 KB
    __shared__ float red[128][2];       // 1 KB

    const int tid = threadIdx.x;
    const int wv = tid >> 6, lane = tid & 63, l15 = lane & 15, l4 = lane >> 4;
    const int wr = wv >> 1, wc = wv & 1;
    const int mt = blockIdx.x & 1023, nh = blockIdx.x >> 10;
    const int m0 = mt * 128, nb = nh * 128;

    f32x4 acc[4][4] = {};

    const int srow = tid >> 3, sc = tid & 7;
    const uint4* ag = encB + (size_t)(m0 + srow) * 64 + sc;
    const uint4* bg = WeB4 + (size_t)(nb + srow) * 64 + sc;

    for (int t = 0; t < 8; ++t) {
        __syncthreads();
#pragma unroll
        for (int g = 0; g < 4; ++g)
            gload16(ag + (size_t)g * 32 * 64 + t * 8, &Ald[g * 256 + tid]);
#pragma unroll
        for (int g = 0; g < 4; ++g)
            gload16(bg + (size_t)g * 32 * 64 + t * 8, &Bld[g * 256 + tid]);
        __syncthreads();
#pragma unroll
        for (int ks = 0; ks < 2; ++ks) {
            const int q = ks * 4 + l4;
            bf16x8 af[4], bfr[4];
#pragma unroll
            for (int mi = 0; mi < 4; ++mi) {
                int row = wr * 64 + mi * 16 + l15;
                af[mi] = *(const bf16x8*)&Ald[row * 8 + (q ^ (row & 7))];
            }
#pragma unroll
            for (int ni = 0; ni < 4; ++ni) {
                int row = wc * 64 + ni * 16 + l15;
                bfr[ni] = *(const bf16x8*)&Bld[row * 8 + (q ^ (row & 7))];
            }
#pragma unroll
            for (int mi = 0; mi < 4; ++mi)
#pragma unroll
                for (int ni = 0; ni < 4; ++ni)
                    acc[mi][ni] = __builtin_amdgcn_mfma_f32_16x16x32_bf16(
                        af[mi], bfr[ni], acc[mi][ni], 0, 0, 0);
        }
    }

    float vv[4];
#pragma unroll
    for (int ni = 0; ni < 4; ++ni) vv[ni] = vvec[nb + wc * 64 + ni * 16 + l15];
#pragma unroll
    for (int mi = 0; mi < 4; ++mi) {
#pragma unroll
        for (int r = 0; r < 4; ++r) {
            const int rowl = wr * 64 + mi * 16 + l4 * 4 + r;  // 0..127
            const int b = rowl & 63;
            float s = 0.f;
#pragma unroll
            for (int ni = 0; ni < 4; ++ni) {
                int n = nb + wc * 64 + ni * 16 + l15;
                float e = acc[mi][ni][r] + qc[b * HD + n];
                s += tanh_fast(e) * vv[ni];
            }
#pragma unroll
            for (int msk = 8; msk >= 1; msk >>= 1)
                s += __shfl_xor(s, msk);
            if (l15 == 0) red[rowl][wc] = s;
        }
    }
    __syncthreads();
    if (tid < 128)
        scp[(size_t)(m0 + tid) * 4 + nh] = red[tid][0] + red[tid][1];
}

// ---------------------------------------------------------------------------
// fallback scores (R2 config, proven 185us): BM=64, BN=512, 512 thr,
// f32 enc + in-loop pack, syncthreads drains. Writes all 4 scp slots.
__global__ __launch_bounds__(512, 4) void scores_f32_kernel(
    const float* __restrict__ enc,
    const uint4* __restrict__ WeB4,     // pre-swizzled
    const float* __restrict__ qc,
    const float* __restrict__ vvec,
    float* __restrict__ scp)
{
    __shared__ uint4 Ald[64 * 8];
    __shared__ uint4 Bld[512 * 8];
    __shared__ float red[64][8];

    const int tid = threadIdx.x;
    const int wv = tid >> 6, lane = tid & 63, l15 = lane & 15, l4 = lane >> 4;
    const int m0 = blockIdx.x * 64;

    f32x4 acc[4][4] = {};

    const int arow = tid >> 3;
    const int ac8 = tid & 7;
    const float* aptr = enc + (size_t)(m0 + arow) * HD + ac8 * 8;
    const int aslot = arow * 8 + (ac8 ^ (arow & 7));

    const int brow = wv * 8 + (lane >> 3);
    // pre-swizzled storage: source chunk == slot chunk (lane&7)
    const uint4* bg = WeB4 + (size_t)brow * 64 + (lane & 7);

    for (int k0 = 0; k0 < HD; k0 += 64) {
        __syncthreads();
        float4 a0 = *(const float4*)(aptr + k0);
        float4 a1 = *(const float4*)(aptr + k0 + 4);
#pragma unroll
        for (int i = 0; i < 8; ++i)
            gload16(bg + (size_t)i * 64 * 64 + k0 / 8, &Bld[i * 512 + tid]);
        uint4 u;
        u.x = pack2(a0.x, a0.y); u.y = pack2(a0.z, a0.w);
        u.z = pack2(a1.x, a1.y); u.w = pack2(a1.z, a1.w);
        Ald[aslot] = u;
        __syncthreads();
#pragma unroll
        for (int ks = 0; ks < 2; ++ks) {
            const int chunk = ks * 4 + l4;
            bf16x8 af[4], bfr[4];
#pragma unroll
            for (int mi = 0; mi < 4; ++mi) {
                int row = mi * 16 + l15;
                af[mi] = *(const bf16x8*)&Ald[row * 8 + (chunk ^ (row & 7))];
            }
#pragma unroll
            for (int ni = 0; ni < 4; ++ni) {
                int row = wv * 64 + ni * 16 + l15;
                bfr[ni] = *(const bf16x8*)&Bld[row * 8 + (chunk ^ (row & 7))];
            }
#pragma unroll
            for (int mi = 0; mi < 4; ++mi)
#pragma unroll
                for (int ni = 0; ni < 4; ++ni)
                    acc[mi][ni] = __builtin_amdgcn_mfma_f32_16x16x32_bf16(
                        af[mi], bfr[ni], acc[mi][ni], 0, 0, 0);
        }
    }

    float vv[4];
#pragma unroll
    for (int ni = 0; ni < 4; ++ni) vv[ni] = vvec[wv * 64 + ni * 16 + l15];
#pragma unroll
    for (int mi = 0; mi < 4; ++mi) {
#pragma unroll
        for (int r = 0; r < 4; ++r) {
            const int rowl = mi * 16 + l4 * 4 + r;
            float s = 0.f;
#pragma unroll
            for (int ni = 0; ni < 4; ++ni) {
                int n = wv * 64 + ni * 16 + l15;
                float e = acc[mi][ni][r] + qc[rowl * HD + n];
                s += tanh_fast(e) * vv[ni];
            }
#pragma unroll
            for (int msk = 8; msk >= 1; msk >>= 1)
                s += __shfl_xor(s, msk);
            if (l15 == 0) red[rowl][wv] = s;
        }
    }
    __syncthreads();
    if (tid < 64) {
        float4 o;
        o.x = red[tid][0] + red[tid][1];
        o.y = red[tid][2] + red[tid][3];
        o.z = red[tid][4] + red[tid][5];
        o.w = red[tid][6] + red[tid][7];
        *(float4*)&scp[(size_t)(m0 + tid) * 4] = o;
    }
}

// ---------------------------------------------------------------------------
// softmax over s per b: sums 4 partials per (s,b); atT layout (B,S)
__global__ void softmax_kernel(const float4* __restrict__ scp,
                               float* __restrict__ atT) {
    const int b = blockIdx.x;
    const int tid = threadIdx.x;  // 256
    __shared__ float sm[256];
    __shared__ float row[SS];
    float m = -1e30f;
    for (int s = tid; s < SS; s += 256) {
        float4 p = scp[s * BB + b];
        float val = (p.x + p.y) + (p.z + p.w);
        row[s] = val;
        m = fmaxf(m, val);
    }
    sm[tid] = m; __syncthreads();
    for (int o = 128; o > 0; o >>= 1) {
        if (tid < o) sm[tid] = fmaxf(sm[tid], sm[tid + o]);
        __syncthreads();
    }
    m = sm[0]; __syncthreads();
    float sum = 0.f;
    for (int s = tid; s < SS; s += 256) {
        float e = __expf(row[s] - m);
        row[s] = e;
        sum += e;
    }
    sm[tid] = sum; __syncthreads();
    for (int o = 128; o > 0; o >>= 1) {
        if (tid < o) sm[tid] += sm[tid + o];
        __syncthreads();
    }
    float inv = 1.f / sm[0];
    for (int s = tid; s < SS; s += 256) atT[(size_t)b * SS + s] = row[s] * inv;
}

// ---------------------------------------------------------------------------
// ctx from bf16 enc (L3-resident): thread owns storage chunk-half, computes
// logical h position (m&7 == b&7, constant per block).
__global__ void ctx_bf_kernel(const uint4* __restrict__ encB,
                              const float* __restrict__ atT,
                              float* __restrict__ part) {
    const int b = blockIdx.x & 63;
    const int chunk = blockIdx.x >> 6;       // 0..63
    const int tid = threadIdx.x;             // 128
    const int sc = tid >> 1, hf = tid & 1;
    const int lc = (sc & ~7) | ((sc & 7) ^ (b & 7));
    float4 a = {0.f, 0.f, 0.f, 0.f};
    const int sbase = chunk * 32;
    const float* wrow = atT + (size_t)b * SS + sbase;
#pragma unroll 4
    for (int si = 0; si < 32; ++si) {
        size_t m = (size_t)(sbase + si) * BB + b;
        float w = wrow[si];
        uint2 e = *(const uint2*)((const char*)(encB + m * 64 + sc) + hf * 8);
        a.x += w * bf2f((unsigned short)(e.x & 0xffff));
        a.y += w * bf2f((unsigned short)(e.x >> 16));
        a.z += w * bf2f((unsigned short)(e.y & 0xffff));
        a.w += w * bf2f((unsigned short)(e.y >> 16));
    }
    *(float4*)(part + ((size_t)chunk * BB + b) * HD + lc * 8 + hf * 4) = a;
}

// fallback ctx from f32 enc
__global__ void ctx_f32_kernel(const float* __restrict__ enc,
                               const float* __restrict__ atT,
                               float* __restrict__ part) {
    const int b = blockIdx.x & 63;
    const int chunk = blockIdx.x >> 6;       // 0..63
    const int h0 = threadIdx.x * 4;          // 128 thr
    float4 a = {0.f, 0.f, 0.f, 0.f};
    const int sbase = chunk * 32;
    const float* wrow = atT + (size_t)b * SS + sbase;
#pragma unroll 8
    for (int si = 0; si < 32; ++si) {
        int s = sbase + si;
        float w = wrow[si];
        float4 e = *(const float4*)(enc + (size_t)(s * BB + b) * HD + h0);
        a.x += w * e.x; a.y += w * e.y; a.z += w * e.z; a.w += w * e.w;
    }
    *(float4*)(part + (size_t)(chunk * BB + b) * HD + h0) = a;
}

__global__ void gather_reduce_kernel(const float* __restrict__ part,
                                     const int* __restrict__ word,
                                     const float* __restrict__ emb,
                                     float* __restrict__ x,
                                     unsigned* __restrict__ y_bf) {
    const int b = blockIdx.x;
    const int h0 = threadIdx.x * 4;          // 128 thr
    float4 a = {0.f, 0.f, 0.f, 0.f};
#pragma unroll 8
    for (int c = 0; c < 64; ++c) {
        float4 p = *(const float4*)(part + (size_t)(c * BB + b) * HD + h0);
        a.x += p.x; a.y += p.y; a.z += p.z; a.w += p.w;
    }
    *(float4*)(x + b * 1024 + HD + h0) = a;
    uint2 u; u.x = pack2(a.x, a.y); u.y = pack2(a.z, a.w);
    *(uint2*)(y_bf + b * 512 + 256 + (h0 >> 1)) = u;
    int w = word[b];
    float4 e = *(const float4*)(emb + (size_t)w * HD + h0);
    *(float4*)(x + b * 1024 + h0) = e;
}

// ---------------------------------------------------------------------------
__global__ void gates_kernel(const float* __restrict__ x,
                             const float* __restrict__ hid,
                             const float* __restrict__ W_ih,
                             const float* __restrict__ W_hh,
                             const float* __restrict__ b_ih,
                             const float* __restrict__ b_hh,
                             float* __restrict__ gi, float* __restrict__ gh) {
    const int tid = threadIdx.x;
    const int b = tid & 63;
    const int j = blockIdx.x * 4 + (tid >> 6);
    float agi = 0.f, agh = 0.f;
    const float* xr = x + b * 1024;
    const float* wr = W_ih + (size_t)j * 1024;
    for (int k = 0; k < 1024; k += 4) {
        float4 xv = *(const float4*)(xr + k);
        float4 w4 = *(const float4*)(wr + k);
        agi += xv.x * w4.x + xv.y * w4.y + xv.z * w4.z + xv.w * w4.w;
    }
    const float* hr = hid + b * HD;
    const float* wh = W_hh + (size_t)j * HD;
    for (int k = 0; k < HD; k += 4) {
        float4 hv = *(const float4*)(hr + k);
        float4 w4 = *(const float4*)(wh + k);
        agh += hv.x * w4.x + hv.y * w4.y + hv.z * w4.z + hv.w * w4.w;
    }
    gi[b * 1536 + j] = agi + b_ih[j];
    gh[b * 1536 + j] = agh + b_hh[j];
}

__global__ void hnew_kernel(const float* __restrict__ gi,
                            const float* __restrict__ gh,
                            const float* __restrict__ hid,
                            float* __restrict__ out_h,
                            unsigned* __restrict__ y_bf) {
    const int b = blockIdx.x;
    const int h = threadIdx.x * 2;           // 256 thr
    float hn[2];
#pragma unroll
    for (int j = 0; j < 2; ++j) {
        int hh = h + j;
        float r = sigmoid_fast(gi[b * 1536 + hh] + gh[b * 1536 + hh]);
        float z = sigmoid_fast(gi[b * 1536 + 512 + hh] + gh[b * 1536 + 512 + hh]);
        float n = tanh_fast(gi[b * 1536 + 1024 + hh] + r * gh[b * 1536 + 1024 + hh]);
        hn[j] = (1.f - z) * n + z * hid[b * HD + hh];
        out_h[b * HD + hh] = hn[j];
    }
    y_bf[b * 512 + (h >> 1)] = pack2(hn[0], hn[1]);
}

// ---------------------------------------------------------------------------
// logits: BM=64, BN=128, BK=64, K=1024 (16 iters), 256 thr (4 waves).
__global__ void logits_kernel(
    const unsigned short* __restrict__ y_bf,  // (64, 1024) bf16
    const float* __restrict__ out_W,          // (V, 1024)
    const float* __restrict__ out_b,
    float* __restrict__ logits)               // (64, V)
{
    __shared__ uint4 Yld[64 * 8];      // 8 KB
    __shared__ uint4 Wld[128 * 8];     // 16 KB
    const int tid = threadIdx.x;
    const int wv = tid >> 6, lane = tid & 63, l15 = lane & 15, l4 = lane >> 4;
    const int n0 = blockIdx.x * 128;

    f32x4 acc[4][2] = {};

    const int s1 = tid, s2 = tid + 256;
    const int r1 = s1 >> 3, g1 = (s1 & 7) ^ (r1 & 7);
    const int r2 = s2 >> 3, g2 = (s2 & 7) ^ (r2 & 7);
    const unsigned short* ya1 = y_bf + (size_t)r1 * 1024 + g1 * 8;
    const unsigned short* ya2 = y_bf + (size_t)r2 * 1024 + g2 * 8;

    const int wr = tid >> 3, wc8 = tid & 7;
    const int wsl = wc8 ^ (wr & 7);
    const float* wp0 = out_W + (size_t)(n0 + wr) * 1024 + wc8 * 8;

    float4 pw[2][8];
#pragma unroll
    for (int i = 0; i < 4; ++i) {      // W(0)
        pw[0][i * 2]     = *(const float4*)(wp0 + (size_t)i * 32768);
        pw[0][i * 2 + 1] = *(const float4*)(wp0 + (size_t)i * 32768 + 4);
    }

#pragma unroll
    for (int t = 0; t < 16; ++t) {
        const int cur = t & 1;
        if (t > 0) {
            asm volatile("s_waitcnt lgkmcnt(0)" ::: "memory");
            __builtin_amdgcn_s_barrier();
        }
        gload16(ya1 + t * 64, &Yld[s1]);
        gload16(ya2 + t * 64, &Yld[s2]);
#pragma unroll
        for (int i = 0; i < 4; ++i) {
            uint4 u;
            u.x = pack2(pw[cur][i * 2].x, pw[cur][i * 2].y);
            u.y = pack2(pw[cur][i * 2].z, pw[cur][i * 2].w);
            u.z = pack2(pw[cur][i * 2 + 1].x, pw[cur][i * 2 + 1].y);
            u.w = pack2(pw[cur][i * 2 + 1].z, pw[cur][i * 2 + 1].w);
            Wld[(wr + 32 * i) * 8 + wsl] = u;
        }
        if (t < 15) {
            const int k1 = (t + 1) * 64;
#pragma unroll
            for (int i = 0; i < 4; ++i) {
                pw[cur ^ 1][i * 2]     = *(const float4*)(wp0 + (size_t)i * 32768 + k1);
                pw[cur ^ 1][i * 2 + 1] = *(const float4*)(wp0 + (size_t)i * 32768 + k1 + 4);
            }
            asm volatile("s_waitcnt vmcnt(8) lgkmcnt(0)" ::: "memory");
        } else {
            asm volatile("s_waitcnt vmcnt(0) lgkmcnt(0)" ::: "memory");
        }
        __builtin_amdgcn_sched_barrier(0);
        __builtin_amdgcn_s_barrier();
        __builtin_amdgcn_sched_barrier(0);

#pragma unroll
        for (int ks = 0; ks < 2; ++ks) {
            const int chunk = ks * 4 + l4;
            bf16x8 af[4], bfr[2];
#pragma unroll
            for (int mi = 0; mi < 4; ++mi) {
                int row = mi * 16 + l15;
                af[mi] = *(const bf16x8*)&Yld[row * 8 + (chunk ^ (row & 7))];
            }
#pragma unroll
            for (int ni = 0; ni < 2; ++ni) {
                int row = wv * 32 + ni * 16 + l15;
                bfr[ni] = *(const bf16x8*)&Wld[row * 8 + (chunk ^ (row & 7))];
            }
#pragma unroll
            for (int mi = 0; mi < 4; ++mi)
#pragma unroll
                for (int ni = 0; ni < 2; ++ni)
                    acc[mi][ni] = __builtin_amdgcn_mfma_f32_16x16x32_bf16(
                        af[mi], bfr[ni], acc[mi][ni], 0, 0, 0);
        }
    }
#pragma unroll
    for (int mi = 0; mi < 4; ++mi) {
#pragma unroll
        for (int r = 0; r < 4; ++r) {
            const int b = mi * 16 + l4 * 4 + r;
#pragma unroll
            for (int ni = 0; ni < 2; ++ni) {
                int n = n0 + wv * 32 + ni * 16 + l15;
                logits[(size_t)b * VV + n] = acc[mi][ni][r] + out_b[n];
            }
        }
    }
}

__global__ void lsm_kernel(float* __restrict__ logits) {
    const int b = blockIdx.x;
    const int tid = threadIdx.x;  // 1024
    __shared__ float sm[1024];
    float* row = logits + (size_t)b * VV;
    float m = -1e30f;
    for (int i = tid; i < VV; i += 1024) m = fmaxf(m, row[i]);
    sm[tid] = m; __syncthreads();
    for (int o = 512; o > 0; o >>= 1) {
        if (tid < o) sm[tid] = fmaxf(sm[tid], sm[tid + o]);
        __syncthreads();
    }
    m = sm[0]; __syncthreads();
    float s = 0.f;
    for (int i = tid; i < VV; i += 1024) s += __expf(row[i] - m);
    sm[tid] = s; __syncthreads();
    for (int o = 512; o > 0; o >>= 1) {
        if (tid < o) sm[tid] += sm[tid + o];
        __syncthreads();
    }
    float lse = m + __logf(sm[0]);
    for (int i = tid; i < VV; i += 1024) row[i] -= lse;
}

// ---------------------------------------------------------------------------
extern "C" void kernel_launch(void* const* d_in, const int* in_sizes, int n_in,
                              void* d_out, int out_size, void* d_ws, size_t ws_size,
                              hipStream_t stream) {
    (void)in_sizes; (void)n_in; (void)out_size;
    const int*   word   = (const int*)d_in[0];
    const float* hid    = (const float*)d_in[1];
    const float* enc    = (const float*)d_in[2];
    const float* emb    = (const float*)d_in[3];
    const float* attn_W = (const float*)d_in[4];
    const float* attn_b = (const float*)d_in[5];
    const float* v      = (const float*)d_in[6];
    const float* W_ih   = (const float*)d_in[7];
    const float* W_hh   = (const float*)d_in[8];
    const float* b_ih   = (const float*)d_in[9];
    const float* b_hh   = (const float*)d_in[10];
    const float* out_W  = (const float*)d_in[11];
    const float* out_b  = (const float*)d_in[12];

    float* out    = (float*)d_out;
    float* logits = out;                         // (B, V)
    float* out_h  = out + (size_t)BB * VV;       // (B, H)

    char* ws0 = (char*)d_ws;
    size_t off = 0;
    float* qc      = (float*)(ws0 + off);    off += 64 * 512 * 4;
    uint4* WeB4    = (uint4*)(ws0 + off);    off += 512 * 512 * 2;
    float* scp     = (float*)(ws0 + off);    off += (size_t)MM * 4 * 4;
    float* atT     = (float*)(ws0 + off);    off += (size_t)MM * 4;
    float* part    = (float*)(ws0 + off);    off += (size_t)64 * 64 * 512 * 4;
    float* x       = (float*)(ws0 + off);    off += 64 * 1024 * 4;
    unsigned* y_bf = (unsigned*)(ws0 + off); off += 64 * 1024 * 2;
    float* gi      = (float*)(ws0 + off);    off += 64 * 1536 * 4;
    float* gh      = (float*)(ws0 + off);    off += 64 * 1536 * 4;
    uint4* encB    = (uint4*)(ws0 + off);    off += (size_t)MM * 512 * 2;
    const bool big = (ws_size >= off);

    prep_kernel<<<128, 256, 0, stream>>>(hid, attn_W, attn_b, qc, WeB4);
    if (big) {
        enc2bf_kernel<<<4096, 256, 0, stream>>>(enc, encB);
        scores_mfma_kernel<<<4096, 256, 0, stream>>>(encB, WeB4, qc, v, scp);
    } else {
        scores_f32_kernel<<<SS, 512, 0, stream>>>(enc, WeB4, qc, v, scp);
    }
    softmax_kernel<<<BB, 256, 0, stream>>>((const float4*)scp, atT);
    if (big) {
        ctx_bf_kernel<<<64 * BB, 128, 0, stream>>>(encB, atT, part);
    } else {
        ctx_f32_kernel<<<64 * BB, 128, 0, stream>>>(enc, atT, part);
    }
    gather_reduce_kernel<<<BB, 128, 0, stream>>>(part, word, emb, x, y_bf);
    gates_kernel<<<384, 256, 0, stream>>>(x, hid, W_ih, W_hh, b_ih, b_hh, gi, gh);
    hnew_kernel<<<BB, 256, 0, stream>>>(gi, gh, hid, out_h, y_bf);
    logits_kernel<<<VV / 128, 256, 0, stream>>>((const unsigned short*)y_bf, out_W, out_b, logits);
    lsm_kernel<<<BB, 1024, 0, stream>>>(logits);
}

// Round 7
// 342.024 us; speedup vs baseline: 1.2814x; 1.1969x over previous
//
#include <hip/hip_runtime.h>
#include <hip/hip_bf16.h>
#include <cstdint>
#include <cstddef>

#define HD 512
#define BB 64
#define SS 2048
#define VV 32000
#define MM (SS*BB)
#define NCH 32          // s-chunks per b (64 rows each)

typedef __attribute__((ext_vector_type(8))) short bf16x8;
typedef __attribute__((ext_vector_type(4))) float f32x4;

static __device__ __forceinline__ unsigned short f2bf(float f) {
    union { float f; unsigned u; } x; x.f = f;
    unsigned r = x.u + 0x7fffu + ((x.u >> 16) & 1u);
    return (unsigned short)(r >> 16);
}
static __device__ __forceinline__ unsigned pack2(float a, float b) {
    return (unsigned)f2bf(a) | ((unsigned)f2bf(b) << 16);
}
static __device__ __forceinline__ float tanh_fast(float x) {
    float e = __expf(2.f * x);
    return 1.f - 2.f / (e + 1.f);
}
static __device__ __forceinline__ float sigmoid_fast(float x) {
    return 1.f / (1.f + __expf(-x));
}
static __device__ __forceinline__ void gload16(const void* g, void* l) {
    __builtin_amdgcn_global_load_lds(
        (const __attribute__((address_space(1))) void*)g,
        (__attribute__((address_space(3))) void*)l, 16, 0, 0);
}

// ---------------------------------------------------------------------------
// prep: qc[b][n] = hid[b]·Wa[n] + attn_b[n];  WeB4 = bf16(attn_W[:, H:])
// stored PRE-SWIZZLED: storage[n][cc] = logical chunk (cc&~7)|((cc&7)^(n&7))
__global__ void prep_kernel(const float* __restrict__ hid,
                            const float* __restrict__ attn_W,
                            const float* __restrict__ attn_b,
                            float* __restrict__ qc,
                            uint4* __restrict__ WeB4) {
    int i = blockIdx.x * 256 + threadIdx.x;      // 0..32767
    int n = i >> 6, b = i & 63;
    const float* hrow = hid + b * HD;
    const float* wrow = attn_W + (size_t)n * (2 * HD);
    float acc = 0.f;
    for (int k = 0; k < HD; k += 4) {
        float4 h4 = *(const float4*)(hrow + k);
        float4 w4 = *(const float4*)(wrow + k);
        acc += h4.x * w4.x + h4.y * w4.y + h4.z * w4.z + h4.w * w4.w;
    }
    qc[b * HD + n] = acc + attn_b[n];
    int col = (i << 3) & 511;
    int cc0 = col >> 3;
    const float* src = attn_W + (size_t)n * (2 * HD) + HD + col;
    float4 f0 = *(const float4*)(src);
    float4 f1 = *(const float4*)(src + 4);
    uint4 p;
    p.x = pack2(f0.x, f0.y); p.y = pack2(f0.z, f0.w);
    p.z = pack2(f1.x, f1.y); p.w = pack2(f1.z, f1.w);
    int ccs = (cc0 & ~7) | ((cc0 & 7) ^ (n & 7));
    WeB4[n * 64 + ccs] = p;
}

// ---------------------------------------------------------------------------
// fused flash-style attention: per block (b, 64-row s-chunk):
//   GEMM (R2 structure): E = encRows @ We^T;  score[s] = sum_n tanh(E+qc)*v
//   then m_loc/exp/l_loc and o[h] = sum_s p[s]*enc[s,b,h] (rows L2-hot).
// Writes flash partials (o, m, l); enc fetched from HBM exactly once.
__global__ __launch_bounds__(512, 2) void fattn_kernel(
    const float* __restrict__ enc,      // (S*B, 512) f32, row = s*64+b
    const uint4* __restrict__ WeB4,     // (512, 64) chunks, pre-swizzled
    const float* __restrict__ qc,       // (64, 512)
    const float* __restrict__ vvec,     // (512)
    float* __restrict__ oP,             // (B*NCH, 512)
    float* __restrict__ mP,             // (B*NCH)
    float* __restrict__ lP)             // (B*NCH)
{
    __shared__ uint4 Ald[64 * 8];       // 8 KB
    __shared__ uint4 Bld[512 * 8];      // 64 KB
    __shared__ float red[64][8];        // 2 KB
    __shared__ float sc_lds[64];
    __shared__ float p_lds[64];

    const int tid = threadIdx.x;
    const int wv = tid >> 6, lane = tid & 63, l15 = lane & 15, l4 = lane >> 4;
    const int b = blockIdx.x & 63;
    const int c = blockIdx.x >> 6;      // 0..31
    const int s0 = c * 64;

    f32x4 acc[4][4] = {};

    const int arow = tid >> 3;          // s-row within chunk, 0..63
    const int ac8 = tid & 7;
    const float* aptr = enc + ((size_t)(s0 + arow) * 64 + b) * HD + ac8 * 8;
    const int aslot = arow * 8 + (ac8 ^ (arow & 7));

    const int brow = wv * 8 + (lane >> 3);
    const uint4* bg = WeB4 + (size_t)brow * 64 + (lane & 7);  // pre-swizzled => linear

    for (int t = 0; t < 8; ++t) {
        __syncthreads();                 // prev iter's ds_reads done
        float4 a0 = *(const float4*)(aptr + t * 64);
        float4 a1 = *(const float4*)(aptr + t * 64 + 4);
#pragma unroll
        for (int i = 0; i < 8; ++i)
            gload16(bg + (size_t)i * 64 * 64 + t * 8, &Bld[i * 512 + tid]);
        uint4 u;
        u.x = pack2(a0.x, a0.y); u.y = pack2(a0.z, a0.w);
        u.z = pack2(a1.x, a1.y); u.w = pack2(a1.z, a1.w);
        Ald[aslot] = u;
        __syncthreads();                 // drains vmcnt (B) + lgkm (A)

#pragma unroll
        for (int ks = 0; ks < 2; ++ks) {
            const int chunk = ks * 4 + l4;
            bf16x8 af[4], bfr[4];
#pragma unroll
            for (int mi = 0; mi < 4; ++mi) {
                int row = mi * 16 + l15;
                af[mi] = *(const bf16x8*)&Ald[row * 8 + (chunk ^ (row & 7))];
            }
#pragma unroll
            for (int ni = 0; ni < 4; ++ni) {
                int row = wv * 64 + ni * 16 + l15;
                bfr[ni] = *(const bf16x8*)&Bld[row * 8 + (chunk ^ (row & 7))];
            }
#pragma unroll
            for (int mi = 0; mi < 4; ++mi)
#pragma unroll
                for (int ni = 0; ni < 4; ++ni)
                    acc[mi][ni] = __builtin_amdgcn_mfma_f32_16x16x32_bf16(
                        af[mi], bfr[ni], acc[mi][ni], 0, 0, 0);
        }
    }

    // scores: tanh + dot v, reduce across 512 n
    float vv[4], qn[4];
#pragma unroll
    for (int ni = 0; ni < 4; ++ni) {
        int n = wv * 64 + ni * 16 + l15;
        vv[ni] = vvec[n];
        qn[ni] = qc[b * HD + n];
    }
#pragma unroll
    for (int mi = 0; mi < 4; ++mi) {
#pragma unroll
        for (int r = 0; r < 4; ++r) {
            const int rowl = mi * 16 + l4 * 4 + r;   // s-row 0..63
            float s = 0.f;
#pragma unroll
            for (int ni = 0; ni < 4; ++ni)
                s += tanh_fast(acc[mi][ni][r] + qn[ni]) * vv[ni];
#pragma unroll
            for (int msk = 8; msk >= 1; msk >>= 1)
                s += __shfl_xor(s, msk);
            if (l15 == 0) red[rowl][wv] = s;
        }
    }
    __syncthreads();
    if (tid < 64) {
        float t = 0.f;
#pragma unroll
        for (int w = 0; w < 8; ++w) t += red[tid][w];
        sc_lds[tid] = t;
    }
    __syncthreads();
    float m_loc = -1e30f;
#pragma unroll 8
    for (int i = 0; i < 64; ++i) m_loc = fmaxf(m_loc, sc_lds[i]);
    if (tid < 64) p_lds[tid] = __expf(sc_lds[tid] - m_loc);
    __syncthreads();

    // context partial: h = tid; rows are L2-hot (fetched by this block's GEMM)
    float o = 0.f;
    const float* erow = enc + ((size_t)s0 * 64 + b) * HD + tid;
#pragma unroll 8
    for (int s = 0; s < 64; ++s)
        o += p_lds[s] * erow[(size_t)s * 64 * HD];
    oP[((size_t)b * NCH + c) * HD + tid] = o;
    if (tid == 0) {
        float l = 0.f;
#pragma unroll 8
        for (int i = 0; i < 64; ++i) l += p_lds[i];
        mP[b * NCH + c] = m_loc;
        lP[b * NCH + c] = l;
    }
}

// ---------------------------------------------------------------------------
// combine flash partials -> context; write x (emb gather + ctx) and y_bf ctx half
__global__ void combine_kernel(const float* __restrict__ oP,
                               const float* __restrict__ mP,
                               const float* __restrict__ lP,
                               const int* __restrict__ word,
                               const float* __restrict__ emb,
                               float* __restrict__ x,
                               unsigned* __restrict__ y_bf) {
    const int b = blockIdx.x;
    const int tid = threadIdx.x;    // 512
    __shared__ float ctx_lds[512];
    float M = -1e30f;
#pragma unroll 8
    for (int c = 0; c < NCH; ++c) M = fmaxf(M, mP[b * NCH + c]);
    float o = 0.f, L = 0.f;
#pragma unroll 4
    for (int c = 0; c < NCH; ++c) {
        float w = __expf(mP[b * NCH + c] - M);
        L += w * lP[b * NCH + c];
        o += w * oP[((size_t)b * NCH + c) * HD + tid];
    }
    float ctx = o / L;
    x[b * 1024 + HD + tid] = ctx;
    ctx_lds[tid] = ctx;
    x[b * 1024 + tid] = emb[(size_t)word[b] * HD + tid];
    __syncthreads();
    if (tid < 256)
        y_bf[b * 512 + 256 + tid] = pack2(ctx_lds[2 * tid], ctx_lds[2 * tid + 1]);
}

// ---------------------------------------------------------------------------
__global__ void gates_kernel(const float* __restrict__ x,
                             const float* __restrict__ hid,
                             const float* __restrict__ W_ih,
                             const float* __restrict__ W_hh,
                             const float* __restrict__ b_ih,
                             const float* __restrict__ b_hh,
                             float* __restrict__ gi, float* __restrict__ gh) {
    const int tid = threadIdx.x;
    const int b = tid & 63;
    const int j = blockIdx.x * 4 + (tid >> 6);
    float agi = 0.f, agh = 0.f;
    const float* xr = x + b * 1024;
    const float* wr = W_ih + (size_t)j * 1024;
    for (int k = 0; k < 1024; k += 4) {
        float4 xv = *(const float4*)(xr + k);
        float4 w4 = *(const float4*)(wr + k);
        agi += xv.x * w4.x + xv.y * w4.y + xv.z * w4.z + xv.w * w4.w;
    }
    const float* hr = hid + b * HD;
    const float* wh = W_hh + (size_t)j * HD;
    for (int k = 0; k < HD; k += 4) {
        float4 hv = *(const float4*)(hr + k);
        float4 w4 = *(const float4*)(wh + k);
        agh += hv.x * w4.x + hv.y * w4.y + hv.z * w4.z + hv.w * w4.w;
    }
    gi[b * 1536 + j] = agi + b_ih[j];
    gh[b * 1536 + j] = agh + b_hh[j];
}

__global__ void hnew_kernel(const float* __restrict__ gi,
                            const float* __restrict__ gh,
                            const float* __restrict__ hid,
                            float* __restrict__ out_h,
                            unsigned* __restrict__ y_bf) {
    const int b = blockIdx.x;
    const int h = threadIdx.x * 2;           // 256 thr
    float hn[2];
#pragma unroll
    for (int j = 0; j < 2; ++j) {
        int hh = h + j;
        float r = sigmoid_fast(gi[b * 1536 + hh] + gh[b * 1536 + hh]);
        float z = sigmoid_fast(gi[b * 1536 + 512 + hh] + gh[b * 1536 + 512 + hh]);
        float n = tanh_fast(gi[b * 1536 + 1024 + hh] + r * gh[b * 1536 + 1024 + hh]);
        hn[j] = (1.f - z) * n + z * hid[b * HD + hh];
        out_h[b * HD + hh] = hn[j];
    }
    y_bf[b * 512 + (h >> 1)] = pack2(hn[0], hn[1]);
}

// ---------------------------------------------------------------------------
// logits: BM=64, BN=128, BK=64, K=1024 (16 iters), 256 thr (4 waves).
__global__ void logits_kernel(
    const unsigned short* __restrict__ y_bf,  // (64, 1024) bf16
    const float* __restrict__ out_W,          // (V, 1024)
    const float* __restrict__ out_b,
    float* __restrict__ logits)               // (64, V)
{
    __shared__ uint4 Yld[64 * 8];      // 8 KB
    __shared__ uint4 Wld[128 * 8];     // 16 KB
    const int tid = threadIdx.x;
    const int wv = tid >> 6, lane = tid & 63, l15 = lane & 15, l4 = lane >> 4;
    const int n0 = blockIdx.x * 128;

    f32x4 acc[4][2] = {};

    const int s1 = tid, s2 = tid + 256;
    const int r1 = s1 >> 3, g1 = (s1 & 7) ^ (r1 & 7);
    const int r2 = s2 >> 3, g2 = (s2 & 7) ^ (r2 & 7);
    const unsigned short* ya1 = y_bf + (size_t)r1 * 1024 + g1 * 8;
    const unsigned short* ya2 = y_bf + (size_t)r2 * 1024 + g2 * 8;

    const int wr = tid >> 3, wc8 = tid & 7;
    const int wsl = wc8 ^ (wr & 7);
    const float* wp0 = out_W + (size_t)(n0 + wr) * 1024 + wc8 * 8;

    float4 pw[2][8];
#pragma unroll
    for (int i = 0; i < 4; ++i) {      // W(0)
        pw[0][i * 2]     = *(const float4*)(wp0 + (size_t)i * 32768);
        pw[0][i * 2 + 1] = *(const float4*)(wp0 + (size_t)i * 32768 + 4);
    }

#pragma unroll
    for (int t = 0; t < 16; ++t) {
        const int cur = t & 1;
        if (t > 0) {
            asm volatile("s_waitcnt lgkmcnt(0)" ::: "memory");
            __builtin_amdgcn_s_barrier();
        }
        gload16(ya1 + t * 64, &Yld[s1]);
        gload16(ya2 + t * 64, &Yld[s2]);
#pragma unroll
        for (int i = 0; i < 4; ++i) {
            uint4 u;
            u.x = pack2(pw[cur][i * 2].x, pw[cur][i * 2].y);
            u.y = pack2(pw[cur][i * 2].z, pw[cur][i * 2].w);
            u.z = pack2(pw[cur][i * 2 + 1].x, pw[cur][i * 2 + 1].y);
            u.w = pack2(pw[cur][i * 2 + 1].z, pw[cur][i * 2 + 1].w);
            Wld[(wr + 32 * i) * 8 + wsl] = u;
        }
        if (t < 15) {
            const int k1 = (t + 1) * 64;
#pragma unroll
            for (int i = 0; i < 4; ++i) {
                pw[cur ^ 1][i * 2]     = *(const float4*)(wp0 + (size_t)i * 32768 + k1);
                pw[cur ^ 1][i * 2 + 1] = *(const float4*)(wp0 + (size_t)i * 32768 + k1 + 4);
            }
            asm volatile("s_waitcnt vmcnt(8) lgkmcnt(0)" ::: "memory");
        } else {
            asm volatile("s_waitcnt vmcnt(0) lgkmcnt(0)" ::: "memory");
        }
        __builtin_amdgcn_sched_barrier(0);
        __builtin_amdgcn_s_barrier();
        __builtin_amdgcn_sched_barrier(0);

#pragma unroll
        for (int ks = 0; ks < 2; ++ks) {
            const int chunk = ks * 4 + l4;
            bf16x8 af[4], bfr[2];
#pragma unroll
            for (int mi = 0; mi < 4; ++mi) {
                int row = mi * 16 + l15;
                af[mi] = *(const bf16x8*)&Yld[row * 8 + (chunk ^ (row & 7))];
            }
#pragma unroll
            for (int ni = 0; ni < 2; ++ni) {
                int row = wv * 32 + ni * 16 + l15;
                bfr[ni] = *(const bf16x8*)&Wld[row * 8 + (chunk ^ (row & 7))];
            }
#pragma unroll
            for (int mi = 0; mi < 4; ++mi)
#pragma unroll
                for (int ni = 0; ni < 2; ++ni)
                    acc[mi][ni] = __builtin_amdgcn_mfma_f32_16x16x32_bf16(
                        af[mi], bfr[ni], acc[mi][ni], 0, 0, 0);
        }
    }
#pragma unroll
    for (int mi = 0; mi < 4; ++mi) {
#pragma unroll
        for (int r = 0; r < 4; ++r) {
            const int b = mi * 16 + l4 * 4 + r;
#pragma unroll
            for (int ni = 0; ni < 2; ++ni) {
                int n = n0 + wv * 32 + ni * 16 + l15;
                logits[(size_t)b * VV + n] = acc[mi][ni][r] + out_b[n];
            }
        }
    }
}

__global__ void lsm_kernel(float* __restrict__ logits) {
    const int b = blockIdx.x;
    const int tid = threadIdx.x;  // 1024
    __shared__ float sm[1024];
    float* row = logits + (size_t)b * VV;
    float m = -1e30f;
    for (int i = tid; i < VV; i += 1024) m = fmaxf(m, row[i]);
    sm[tid] = m; __syncthreads();
    for (int o = 512; o > 0; o >>= 1) {
        if (tid < o) sm[tid] = fmaxf(sm[tid], sm[tid + o]);
        __syncthreads();
    }
    m = sm[0]; __syncthreads();
    float s = 0.f;
    for (int i = tid; i < VV; i += 1024) s += __expf(row[i] - m);
    sm[tid] = s; __syncthreads();
    for (int o = 512; o > 0; o >>= 1) {
        if (tid < o) sm[tid] += sm[tid + o];
        __syncthreads();
    }
    float lse = m + __logf(sm[0]);
    for (int i = tid; i < VV; i += 1024) row[i] -= lse;
}

// ---------------------------------------------------------------------------
extern "C" void kernel_launch(void* const* d_in, const int* in_sizes, int n_in,
                              void* d_out, int out_size, void* d_ws, size_t ws_size,
                              hipStream_t stream) {
    (void)in_sizes; (void)n_in; (void)out_size; (void)ws_size;
    const int*   word   = (const int*)d_in[0];
    const float* hid    = (const float*)d_in[1];
    const float* enc    = (const float*)d_in[2];
    const float* emb    = (const float*)d_in[3];
    const float* attn_W = (const float*)d_in[4];
    const float* attn_b = (const float*)d_in[5];
    const float* v      = (const float*)d_in[6];
    const float* W_ih   = (const float*)d_in[7];
    const float* W_hh   = (const float*)d_in[8];
    const float* b_ih   = (const float*)d_in[9];
    const float* b_hh   = (const float*)d_in[10];
    const float* out_W  = (const float*)d_in[11];
    const float* out_b  = (const float*)d_in[12];

    float* out    = (float*)d_out;
    float* logits = out;                         // (B, V)
    float* out_h  = out + (size_t)BB * VV;       // (B, H)

    char* ws0 = (char*)d_ws;
    size_t off = 0;
    float* qc      = (float*)(ws0 + off);    off += 64 * 512 * 4;
    uint4* WeB4    = (uint4*)(ws0 + off);    off += 512 * 512 * 2;
    float* oP      = (float*)(ws0 + off);    off += (size_t)BB * NCH * HD * 4;
    float* mP      = (float*)(ws0 + off);    off += BB * NCH * 4;
    float* lP      = (float*)(ws0 + off);    off += BB * NCH * 4;
    float* x       = (float*)(ws0 + off);    off += 64 * 1024 * 4;
    unsigned* y_bf = (unsigned*)(ws0 + off); off += 64 * 1024 * 2;
    float* gi      = (float*)(ws0 + off);    off += 64 * 1536 * 4;
    float* gh      = (float*)(ws0 + off);    off += 64 * 1536 * 4;

    prep_kernel<<<128, 256, 0, stream>>>(hid, attn_W, attn_b, qc, WeB4);
    fattn_kernel<<<BB * NCH, 512, 0, stream>>>(enc, WeB4, qc, v, oP, mP, lP);
    combine_kernel<<<BB, 512, 0, stream>>>(oP, mP, lP, word, emb, x, y_bf);
    gates_kernel<<<384, 256, 0, stream>>>(x, hid, W_ih, W_hh, b_ih, b_hh, gi, gh);
    hnew_kernel<<<BB, 256, 0, stream>>>(gi, gh, hid, out_h, y_bf);
    logits_kernel<<<VV / 128, 256, 0, stream>>>((const unsigned short*)y_bf, out_W, out_b, logits);
    lsm_kernel<<<BB, 1024, 0, stream>>>(logits);
}

// Round 8
// 333.562 us; speedup vs baseline: 1.3139x; 1.0254x over previous
//
#include <hip/hip_runtime.h>
#include <hip/hip_bf16.h>
#include <cstdint>
#include <cstddef>

#define HD 512
#define BB 64
#define SS 2048
#define VV 32000
#define MM (SS*BB)
#define NCH 32          // s-chunks per b (64 rows each)

typedef __attribute__((ext_vector_type(8))) short bf16x8;
typedef __attribute__((ext_vector_type(4))) float f32x4;

static __device__ __forceinline__ unsigned short f2bf(float f) {
    union { float f; unsigned u; } x; x.f = f;
    unsigned r = x.u + 0x7fffu + ((x.u >> 16) & 1u);
    return (unsigned short)(r >> 16);
}
static __device__ __forceinline__ unsigned pack2(float a, float b) {
    return (unsigned)f2bf(a) | ((unsigned)f2bf(b) << 16);
}
static __device__ __forceinline__ float rcp_fast(float x) {
    float r; asm("v_rcp_f32 %0, %1" : "=v"(r) : "v"(x)); return r;
}
static __device__ __forceinline__ float tanh_fast(float x) {
    float e = __expf(2.f * x);
    return 1.f - 2.f * rcp_fast(e + 1.f);
}
static __device__ __forceinline__ float sigmoid_fast(float x) {
    return 1.f / (1.f + __expf(-x));
}
static __device__ __forceinline__ void gload16(const void* g, void* l) {
    __builtin_amdgcn_global_load_lds(
        (const __attribute__((address_space(1))) void*)g,
        (__attribute__((address_space(3))) void*)l, 16, 0, 0);
}

// ---------------------------------------------------------------------------
// prep: qc[b][n] = hid[b]·Wa[n] + attn_b[n];  WeB4 = bf16(attn_W[:, H:])
// stored PRE-SWIZZLED: storage[n][cc] = logical chunk (cc&~7)|((cc&7)^(n&7))
__global__ void prep_kernel(const float* __restrict__ hid,
                            const float* __restrict__ attn_W,
                            const float* __restrict__ attn_b,
                            float* __restrict__ qc,
                            uint4* __restrict__ WeB4) {
    int i = blockIdx.x * 256 + threadIdx.x;      // 0..32767
    int n = i >> 6, b = i & 63;
    const float* hrow = hid + b * HD;
    const float* wrow = attn_W + (size_t)n * (2 * HD);
    float acc = 0.f;
    for (int k = 0; k < HD; k += 4) {
        float4 h4 = *(const float4*)(hrow + k);
        float4 w4 = *(const float4*)(wrow + k);
        acc += h4.x * w4.x + h4.y * w4.y + h4.z * w4.z + h4.w * w4.w;
    }
    qc[b * HD + n] = acc + attn_b[n];
    int col = (i << 3) & 511;
    int cc0 = col >> 3;
    const float* src = attn_W + (size_t)n * (2 * HD) + HD + col;
    float4 f0 = *(const float4*)(src);
    float4 f1 = *(const float4*)(src + 4);
    uint4 p;
    p.x = pack2(f0.x, f0.y); p.y = pack2(f0.z, f0.w);
    p.z = pack2(f1.x, f1.y); p.w = pack2(f1.z, f1.w);
    int ccs = (cc0 & ~7) | ((cc0 & 7) ^ (n & 7));
    WeB4[n * 64 + ccs] = p;
}

// ---------------------------------------------------------------------------
// fused attention: per block (b, 64-row s-chunk):
//   GEMM: E = encRows @ We^T;  score[s] = sum_n tanh(E+qc)*v
//   p = exp(score) directly (|score| <= sum|v| ~ 20, no max needed)
//   o[h] = sum_s p[s]*enc[s,b,h] (rows L2-hot), parallel across waves.
__global__ __launch_bounds__(512, 2) void fattn_kernel(
    const float* __restrict__ enc,      // (S*B, 512) f32, row = s*64+b
    const uint4* __restrict__ WeB4,     // (512, 64) chunks, pre-swizzled
    const float* __restrict__ qc,       // (64, 512)
    const float* __restrict__ vvec,     // (512)
    float* __restrict__ oP,             // (B*NCH, 512)
    float* __restrict__ lP)             // (B*NCH)
{
    __shared__ char smem[8192 + 65536 + 2048 + 256];
    uint4* Ald = (uint4*)smem;                              // 8 KB
    uint4* Bld = (uint4*)(smem + 8192);                     // 64 KB
    float (*red)[8] = (float(*)[8])(smem + 8192 + 65536);   // 2 KB
    float* p_lds = (float*)(smem + 8192 + 65536 + 2048);    // 256 B
    float* opart = (float*)(smem + 8192);                   // aliases Bld (16 KB)

    const int tid = threadIdx.x;
    const int wv = tid >> 6, lane = tid & 63, l15 = lane & 15, l4 = lane >> 4;
    const int b = blockIdx.x & 63;
    const int c = blockIdx.x >> 6;      // 0..31
    const int s0 = c * 64;

    f32x4 acc[4][4] = {};

    const int arow = tid >> 3;          // s-row within chunk, 0..63
    const int ac8 = tid & 7;
    const float* aptr = enc + ((size_t)(s0 + arow) * 64 + b) * HD + ac8 * 8;
    const int aslot = arow * 8 + (ac8 ^ (arow & 7));

    const int brow = wv * 8 + (lane >> 3);
    const uint4* bg = WeB4 + (size_t)brow * 64 + (lane & 7);  // pre-swizzled => linear

    for (int t = 0; t < 8; ++t) {
        __syncthreads();                 // prev iter's ds_reads done
        float4 a0 = *(const float4*)(aptr + t * 64);
        float4 a1 = *(const float4*)(aptr + t * 64 + 4);
#pragma unroll
        for (int i = 0; i < 8; ++i)
            gload16(bg + (size_t)i * 64 * 64 + t * 8, &Bld[i * 512 + tid]);
        uint4 u;
        u.x = pack2(a0.x, a0.y); u.y = pack2(a0.z, a0.w);
        u.z = pack2(a1.x, a1.y); u.w = pack2(a1.z, a1.w);
        Ald[aslot] = u;
        __syncthreads();                 // drains vmcnt (B) + lgkm (A)

#pragma unroll
        for (int ks = 0; ks < 2; ++ks) {
            const int chunk = ks * 4 + l4;
            bf16x8 af[4], bfr[4];
#pragma unroll
            for (int mi = 0; mi < 4; ++mi) {
                int row = mi * 16 + l15;
                af[mi] = *(const bf16x8*)&Ald[row * 8 + (chunk ^ (row & 7))];
            }
#pragma unroll
            for (int ni = 0; ni < 4; ++ni) {
                int row = wv * 64 + ni * 16 + l15;
                bfr[ni] = *(const bf16x8*)&Bld[row * 8 + (chunk ^ (row & 7))];
            }
#pragma unroll
            for (int mi = 0; mi < 4; ++mi)
#pragma unroll
                for (int ni = 0; ni < 4; ++ni)
                    acc[mi][ni] = __builtin_amdgcn_mfma_f32_16x16x32_bf16(
                        af[mi], bfr[ni], acc[mi][ni], 0, 0, 0);
        }
    }

    // scores: tanh + dot v, reduce across 512 n
    float vv[4], qn[4];
#pragma unroll
    for (int ni = 0; ni < 4; ++ni) {
        int n = wv * 64 + ni * 16 + l15;
        vv[ni] = vvec[n];
        qn[ni] = qc[b * HD + n];
    }
#pragma unroll
    for (int mi = 0; mi < 4; ++mi) {
#pragma unroll
        for (int r = 0; r < 4; ++r) {
            const int rowl = mi * 16 + l4 * 4 + r;   // s-row 0..63
            float s = 0.f;
#pragma unroll
            for (int ni = 0; ni < 4; ++ni)
                s += tanh_fast(acc[mi][ni][r] + qn[ni]) * vv[ni];
#pragma unroll
            for (int msk = 8; msk >= 1; msk >>= 1)
                s += __shfl_xor(s, msk);
            if (l15 == 0) red[rowl][wv] = s;
        }
    }
    __syncthreads();
    if (tid < 64) {                      // wave 0
        float t = ((red[tid][0] + red[tid][1]) + (red[tid][2] + red[tid][3]))
                + ((red[tid][4] + red[tid][5]) + (red[tid][6] + red[tid][7]));
        float p = __expf(t);             // |t| <= sum|v| ~ 20: safe
        p_lds[tid] = p;
        float l = p;
#pragma unroll
        for (int msk = 32; msk >= 1; msk >>= 1) l += __shfl_xor(l, msk);
        if (tid == 0) lP[b * NCH + c] = l;
    }
    __syncthreads();

    // o-phase: wave wv owns s-rows wv*8..wv*8+7, lane owns h = lane*8..lane*8+7
    float o8[8] = {};
    const float* ebase = enc + ((size_t)(s0 + wv * 8) * 64 + b) * HD + lane * 8;
#pragma unroll
    for (int i = 0; i < 8; ++i) {
        float w = p_lds[wv * 8 + i];
        const float* ep = ebase + (size_t)i * 64 * HD;
        float4 e0 = *(const float4*)(ep);
        float4 e1 = *(const float4*)(ep + 4);
        o8[0] += w * e0.x; o8[1] += w * e0.y; o8[2] += w * e0.z; o8[3] += w * e0.w;
        o8[4] += w * e1.x; o8[5] += w * e1.y; o8[6] += w * e1.z; o8[7] += w * e1.w;
    }
    {
        float4* dst = (float4*)&opart[wv * 512 + lane * 8];
        float4 w0 = {o8[0], o8[1], o8[2], o8[3]};
        float4 w1 = {o8[4], o8[5], o8[6], o8[7]};
        dst[0] = w0; dst[1] = w1;
    }
    __syncthreads();
    float o = 0.f;
#pragma unroll
    for (int w = 0; w < 8; ++w) o += opart[w * 512 + tid];
    oP[((size_t)b * NCH + c) * HD + tid] = o;
}

// ---------------------------------------------------------------------------
// combine partials -> context; write x (emb gather + ctx) and y_bf ctx half
__global__ void combine_kernel(const float* __restrict__ oP,
                               const float* __restrict__ lP,
                               const int* __restrict__ word,
                               const float* __restrict__ emb,
                               float* __restrict__ x,
                               unsigned* __restrict__ y_bf) {
    const int b = blockIdx.x;
    const int tid = threadIdx.x;    // 512
    __shared__ float ctx_lds[512];
    float L = 0.f;
#pragma unroll 8
    for (int c = 0; c < NCH; ++c) L += lP[b * NCH + c];
    float o = 0.f;
#pragma unroll 4
    for (int c = 0; c < NCH; ++c)
        o += oP[((size_t)b * NCH + c) * HD + tid];
    float ctx = o / L;
    x[b * 1024 + HD + tid] = ctx;
    ctx_lds[tid] = ctx;
    x[b * 1024 + tid] = emb[(size_t)word[b] * HD + tid];
    __syncthreads();
    if (tid < 256)
        y_bf[b * 512 + 256 + tid] = pack2(ctx_lds[2 * tid], ctx_lds[2 * tid + 1]);
}

// ---------------------------------------------------------------------------
__global__ void gates_kernel(const float* __restrict__ x,
                             const float* __restrict__ hid,
                             const float* __restrict__ W_ih,
                             const float* __restrict__ W_hh,
                             const float* __restrict__ b_ih,
                             const float* __restrict__ b_hh,
                             float* __restrict__ gi, float* __restrict__ gh) {
    const int tid = threadIdx.x;
    const int b = tid & 63;
    const int j = blockIdx.x * 4 + (tid >> 6);
    float agi = 0.f, agh = 0.f;
    const float* xr = x + b * 1024;
    const float* wr = W_ih + (size_t)j * 1024;
    for (int k = 0; k < 1024; k += 4) {
        float4 xv = *(const float4*)(xr + k);
        float4 w4 = *(const float4*)(wr + k);
        agi += xv.x * w4.x + xv.y * w4.y + xv.z * w4.z + xv.w * w4.w;
    }
    const float* hr = hid + b * HD;
    const float* wh = W_hh + (size_t)j * HD;
    for (int k = 0; k < HD; k += 4) {
        float4 hv = *(const float4*)(hr + k);
        float4 w4 = *(const float4*)(wh + k);
        agh += hv.x * w4.x + hv.y * w4.y + hv.z * w4.z + hv.w * w4.w;
    }
    gi[b * 1536 + j] = agi + b_ih[j];
    gh[b * 1536 + j] = agh + b_hh[j];
}

__global__ void hnew_kernel(const float* __restrict__ gi,
                            const float* __restrict__ gh,
                            const float* __restrict__ hid,
                            float* __restrict__ out_h,
                            unsigned* __restrict__ y_bf) {
    const int b = blockIdx.x;
    const int h = threadIdx.x * 2;           // 256 thr
    float hn[2];
#pragma unroll
    for (int j = 0; j < 2; ++j) {
        int hh = h + j;
        float r = sigmoid_fast(gi[b * 1536 + hh] + gh[b * 1536 + hh]);
        float z = sigmoid_fast(gi[b * 1536 + 512 + hh] + gh[b * 1536 + 512 + hh]);
        float n = tanh_fast(gi[b * 1536 + 1024 + hh] + r * gh[b * 1536 + 1024 + hh]);
        hn[j] = (1.f - z) * n + z * hid[b * HD + hh];
        out_h[b * HD + hh] = hn[j];
    }
    y_bf[b * 512 + (h >> 1)] = pack2(hn[0], hn[1]);
}

// ---------------------------------------------------------------------------
// logits: BM=64, BN=128, BK=64, K=1024 (16 iters), 256 thr (4 waves).
__global__ void logits_kernel(
    const unsigned short* __restrict__ y_bf,  // (64, 1024) bf16
    const float* __restrict__ out_W,          // (V, 1024)
    const float* __restrict__ out_b,
    float* __restrict__ logits)               // (64, V)
{
    __shared__ uint4 Yld[64 * 8];      // 8 KB
    __shared__ uint4 Wld[128 * 8];     // 16 KB
    const int tid = threadIdx.x;
    const int wv = tid >> 6, lane = tid & 63, l15 = lane & 15, l4 = lane >> 4;
    const int n0 = blockIdx.x * 128;

    f32x4 acc[4][2] = {};

    const int s1 = tid, s2 = tid + 256;
    const int r1 = s1 >> 3, g1 = (s1 & 7) ^ (r1 & 7);
    const int r2 = s2 >> 3, g2 = (s2 & 7) ^ (r2 & 7);
    const unsigned short* ya1 = y_bf + (size_t)r1 * 1024 + g1 * 8;
    const unsigned short* ya2 = y_bf + (size_t)r2 * 1024 + g2 * 8;

    const int wr = tid >> 3, wc8 = tid & 7;
    const int wsl = wc8 ^ (wr & 7);
    const float* wp0 = out_W + (size_t)(n0 + wr) * 1024 + wc8 * 8;

    float4 pw[2][8];
#pragma unroll
    for (int i = 0; i < 4; ++i) {      // W(0)
        pw[0][i * 2]     = *(const float4*)(wp0 + (size_t)i * 32768);
        pw[0][i * 2 + 1] = *(const float4*)(wp0 + (size_t)i * 32768 + 4);
    }

#pragma unroll
    for (int t = 0; t < 16; ++t) {
        const int cur = t & 1;
        if (t > 0) {
            asm volatile("s_waitcnt lgkmcnt(0)" ::: "memory");
            __builtin_amdgcn_s_barrier();
        }
        gload16(ya1 + t * 64, &Yld[s1]);
        gload16(ya2 + t * 64, &Yld[s2]);
#pragma unroll
        for (int i = 0; i < 4; ++i) {
            uint4 u;
            u.x = pack2(pw[cur][i * 2].x, pw[cur][i * 2].y);
            u.y = pack2(pw[cur][i * 2].z, pw[cur][i * 2].w);
            u.z = pack2(pw[cur][i * 2 + 1].x, pw[cur][i * 2 + 1].y);
            u.w = pack2(pw[cur][i * 2 + 1].z, pw[cur][i * 2 + 1].w);
            Wld[(wr + 32 * i) * 8 + wsl] = u;
        }
        if (t < 15) {
            const int k1 = (t + 1) * 64;
#pragma unroll
            for (int i = 0; i < 4; ++i) {
                pw[cur ^ 1][i * 2]     = *(const float4*)(wp0 + (size_t)i * 32768 + k1);
                pw[cur ^ 1][i * 2 + 1] = *(const float4*)(wp0 + (size_t)i * 32768 + k1 + 4);
            }
            asm volatile("s_waitcnt vmcnt(8) lgkmcnt(0)" ::: "memory");
        } else {
            asm volatile("s_waitcnt vmcnt(0) lgkmcnt(0)" ::: "memory");
        }
        __builtin_amdgcn_sched_barrier(0);
        __builtin_amdgcn_s_barrier();
        __builtin_amdgcn_sched_barrier(0);

#pragma unroll
        for (int ks = 0; ks < 2; ++ks) {
            const int chunk = ks * 4 + l4;
            bf16x8 af[4], bfr[2];
#pragma unroll
            for (int mi = 0; mi < 4; ++mi) {
                int row = mi * 16 + l15;
                af[mi] = *(const bf16x8*)&Yld[row * 8 + (chunk ^ (row & 7))];
            }
#pragma unroll
            for (int ni = 0; ni < 2; ++ni) {
                int row = wv * 32 + ni * 16 + l15;
                bfr[ni] = *(const bf16x8*)&Wld[row * 8 + (chunk ^ (row & 7))];
            }
#pragma unroll
            for (int mi = 0; mi < 4; ++mi)
#pragma unroll
                for (int ni = 0; ni < 2; ++ni)
                    acc[mi][ni] = __builtin_amdgcn_mfma_f32_16x16x32_bf16(
                        af[mi], bfr[ni], acc[mi][ni], 0, 0, 0);
        }
    }
#pragma unroll
    for (int mi = 0; mi < 4; ++mi) {
#pragma unroll
        for (int r = 0; r < 4; ++r) {
            const int b = mi * 16 + l4 * 4 + r;
#pragma unroll
            for (int ni = 0; ni < 2; ++ni) {
                int n = n0 + wv * 32 + ni * 16 + l15;
                logits[(size_t)b * VV + n] = acc[mi][ni][r] + out_b[n];
            }
        }
    }
}

__global__ void lsm_kernel(float* __restrict__ logits) {
    const int b = blockIdx.x;
    const int tid = threadIdx.x;  // 1024
    __shared__ float sm[1024];
    float* row = logits + (size_t)b * VV;
    float m = -1e30f;
    for (int i = tid; i < VV; i += 1024) m = fmaxf(m, row[i]);
    sm[tid] = m; __syncthreads();
    for (int o = 512; o > 0; o >>= 1) {
        if (tid < o) sm[tid] = fmaxf(sm[tid], sm[tid + o]);
        __syncthreads();
    }
    m = sm[0]; __syncthreads();
    float s = 0.f;
    for (int i = tid; i < VV; i += 1024) s += __expf(row[i] - m);
    sm[tid] = s; __syncthreads();
    for (int o = 512; o > 0; o >>= 1) {
        if (tid < o) sm[tid] += sm[tid + o];
        __syncthreads();
    }
    float lse = m + __logf(sm[0]);
    for (int i = tid; i < VV; i += 1024) row[i] -= lse;
}

// ---------------------------------------------------------------------------
extern "C" void kernel_launch(void* const* d_in, const int* in_sizes, int n_in,
                              void* d_out, int out_size, void* d_ws, size_t ws_size,
                              hipStream_t stream) {
    (void)in_sizes; (void)n_in; (void)out_size; (void)ws_size;
    const int*   word   = (const int*)d_in[0];
    const float* hid    = (const float*)d_in[1];
    const float* enc    = (const float*)d_in[2];
    const float* emb    = (const float*)d_in[3];
    const float* attn_W = (const float*)d_in[4];
    const float* attn_b = (const float*)d_in[5];
    const float* v      = (const float*)d_in[6];
    const float* W_ih   = (const float*)d_in[7];
    const float* W_hh   = (const float*)d_in[8];
    const float* b_ih   = (const float*)d_in[9];
    const float* b_hh   = (const float*)d_in[10];
    const float* out_W  = (const float*)d_in[11];
    const float* out_b  = (const float*)d_in[12];

    float* out    = (float*)d_out;
    float* logits = out;                         // (B, V)
    float* out_h  = out + (size_t)BB * VV;       // (B, H)

    char* ws0 = (char*)d_ws;
    size_t off = 0;
    float* qc      = (float*)(ws0 + off);    off += 64 * 512 * 4;
    uint4* WeB4    = (uint4*)(ws0 + off);    off += 512 * 512 * 2;
    float* oP      = (float*)(ws0 + off);    off += (size_t)BB * NCH * HD * 4;
    float* lP      = (float*)(ws0 + off);    off += BB * NCH * 4;
    float* x       = (float*)(ws0 + off);    off += 64 * 1024 * 4;
    unsigned* y_bf = (unsigned*)(ws0 + off); off += 64 * 1024 * 2;
    float* gi      = (float*)(ws0 + off);    off += 64 * 1536 * 4;
    float* gh      = (float*)(ws0 + off);    off += 64 * 1536 * 4;

    prep_kernel<<<128, 256, 0, stream>>>(hid, attn_W, attn_b, qc, WeB4);
    fattn_kernel<<<BB * NCH, 512, 0, stream>>>(enc, WeB4, qc, v, oP, lP);
    combine_kernel<<<BB, 512, 0, stream>>>(oP, lP, word, emb, x, y_bf);
    gates_kernel<<<384, 256, 0, stream>>>(x, hid, W_ih, W_hh, b_ih, b_hh, gi, gh);
    hnew_kernel<<<BB, 256, 0, stream>>>(gi, gh, hid, out_h, y_bf);
    logits_kernel<<<VV / 128, 256, 0, stream>>>((const unsigned short*)y_bf, out_W, out_b, logits);
    lsm_kernel<<<BB, 1024, 0, stream>>>(logits);
}

// Round 9
// 328.193 us; speedup vs baseline: 1.3354x; 1.0164x over previous
//
#include <hip/hip_runtime.h>
#include <hip/hip_bf16.h>
#include <cstdint>
#include <cstddef>

#define HD 512
#define BB 64
#define SS 2048
#define VV 32000
#define MM (SS*BB)
#define NCH 32          // s-chunks per b (64 rows each)

typedef __attribute__((ext_vector_type(8))) short bf16x8;
typedef __attribute__((ext_vector_type(4))) float f32x4;

// v_cvt_pk_bf16_f32: dst = {lo16: bf16(a), hi16: bf16(b)}  (RNE)
static __device__ __forceinline__ unsigned pack2(float a, float b) {
    unsigned r;
    asm("v_cvt_pk_bf16_f32 %0, %1, %2" : "=v"(r) : "v"(a), "v"(b));
    return r;
}
static __device__ __forceinline__ float rcp_fast(float x) {
    float r; asm("v_rcp_f32 %0, %1" : "=v"(r) : "v"(x)); return r;
}
static __device__ __forceinline__ float tanh_fast(float x) {
    float e = __expf(2.f * x);
    return 1.f - 2.f * rcp_fast(e + 1.f);
}
static __device__ __forceinline__ float sigmoid_fast(float x) {
    return 1.f / (1.f + __expf(-x));
}
static __device__ __forceinline__ void gload16(const void* g, void* l) {
    __builtin_amdgcn_global_load_lds(
        (const __attribute__((address_space(1))) void*)g,
        (__attribute__((address_space(3))) void*)l, 16, 0, 0);
}

// ---------------------------------------------------------------------------
// prep: qc[b][n] = hid[b]·Wa[n] + attn_b[n];  WeB4 = bf16(attn_W[:, H:])
// stored PRE-SWIZZLED: storage[n][cc] = logical chunk (cc&~7)|((cc&7)^(n&7))
__global__ void prep_kernel(const float* __restrict__ hid,
                            const float* __restrict__ attn_W,
                            const float* __restrict__ attn_b,
                            float* __restrict__ qc,
                            uint4* __restrict__ WeB4) {
    int i = blockIdx.x * 256 + threadIdx.x;      // 0..32767
    int n = i >> 6, b = i & 63;
    const float* hrow = hid + b * HD;
    const float* wrow = attn_W + (size_t)n * (2 * HD);
    float acc = 0.f;
    for (int k = 0; k < HD; k += 4) {
        float4 h4 = *(const float4*)(hrow + k);
        float4 w4 = *(const float4*)(wrow + k);
        acc += h4.x * w4.x + h4.y * w4.y + h4.z * w4.z + h4.w * w4.w;
    }
    qc[b * HD + n] = acc + attn_b[n];
    int col = (i << 3) & 511;
    int cc0 = col >> 3;
    const float* src = attn_W + (size_t)n * (2 * HD) + HD + col;
    float4 f0 = *(const float4*)(src);
    float4 f1 = *(const float4*)(src + 4);
    uint4 p;
    p.x = pack2(f0.x, f0.y); p.y = pack2(f0.z, f0.w);
    p.z = pack2(f1.x, f1.y); p.w = pack2(f1.z, f1.w);
    int ccs = (cc0 & ~7) | ((cc0 & 7) ^ (n & 7));
    WeB4[n * 64 + ccs] = p;
}

// ---------------------------------------------------------------------------
// fused attention, pipelined: per block (b, 64-row s-chunk).
// Queue-ordered counted vmcnt: A(t+1) regs fly across barriers; per-iter
// exposure is only the B L2 transfer.
__global__ __launch_bounds__(512, 2) void fattn_kernel(
    const float* __restrict__ enc,      // (S*B, 512) f32, row = s*64+b
    const uint4* __restrict__ WeB4,     // (512, 64) chunks, pre-swizzled
    const float* __restrict__ qc,       // (64, 512)
    const float* __restrict__ vvec,     // (512)
    float* __restrict__ oP,             // (B*NCH, 512)
    float* __restrict__ lP)             // (B*NCH)
{
    __shared__ char smem[8192 + 65536 + 2048 + 256];
    uint4* Ald = (uint4*)smem;                              // 8 KB
    uint4* Bld = (uint4*)(smem + 8192);                     // 64 KB
    float (*red)[8] = (float(*)[8])(smem + 8192 + 65536);   // 2 KB
    float* p_lds = (float*)(smem + 8192 + 65536 + 2048);    // 256 B
    float* opart = (float*)(smem + 8192);                   // aliases Bld (16 KB)

    const int tid = threadIdx.x;
    const int wv = tid >> 6, lane = tid & 63, l15 = lane & 15, l4 = lane >> 4;
    const int b = blockIdx.x & 63;
    const int c = blockIdx.x >> 6;      // 0..31
    const int s0 = c * 64;

    f32x4 acc[4][4] = {};

    const int arow = tid >> 3;          // s-row within chunk, 0..63
    const int ac8 = tid & 7;
    const float* aptr = enc + ((size_t)(s0 + arow) * 64 + b) * HD + ac8 * 8;
    const int aslot = arow * 8 + (ac8 ^ (arow & 7));

    const int brow = wv * 8 + (lane >> 3);
    const uint4* bg = WeB4 + (size_t)brow * 64 + (lane & 7);  // pre-swizzled => linear

    float4 pa[2][2];
    // ---- prologue: A(0) regs, B(0) gloads, A(1) regs, pack A(0)
    pa[0][0] = *(const float4*)(aptr);
    pa[0][1] = *(const float4*)(aptr + 4);
#pragma unroll
    for (int i = 0; i < 8; ++i)
        gload16(bg + (size_t)i * 4096, &Bld[i * 512 + tid]);
    pa[1][0] = *(const float4*)(aptr + 64);
    pa[1][1] = *(const float4*)(aptr + 68);
    {
        uint4 u;
        u.x = pack2(pa[0][0].x, pa[0][0].y);
        u.y = pack2(pa[0][0].z, pa[0][0].w);
        u.z = pack2(pa[0][1].x, pa[0][1].y);
        u.w = pack2(pa[0][1].z, pa[0][1].w);
        Ald[aslot] = u;                  // compiler waits pa[0] (vmcnt 10)
    }
    asm volatile("s_waitcnt vmcnt(2) lgkmcnt(0)" ::: "memory");  // B(0) done; pa[1] flies
    __builtin_amdgcn_s_barrier();
    __builtin_amdgcn_sched_barrier(0);

#pragma unroll
    for (int t = 0; t < 8; ++t) {
        const int cur = t & 1;
        // ---- compute(t)
#pragma unroll
        for (int ks = 0; ks < 2; ++ks) {
            const int chunk = ks * 4 + l4;
            bf16x8 af[4], bfr[4];
#pragma unroll
            for (int mi = 0; mi < 4; ++mi) {
                int row = mi * 16 + l15;
                af[mi] = *(const bf16x8*)&Ald[row * 8 + (chunk ^ (row & 7))];
            }
#pragma unroll
            for (int ni = 0; ni < 4; ++ni) {
                int row = wv * 64 + ni * 16 + l15;
                bfr[ni] = *(const bf16x8*)&Bld[row * 8 + (chunk ^ (row & 7))];
            }
#pragma unroll
            for (int mi = 0; mi < 4; ++mi)
#pragma unroll
                for (int ni = 0; ni < 4; ++ni)
                    acc[mi][ni] = __builtin_amdgcn_mfma_f32_16x16x32_bf16(
                        af[mi], bfr[ni], acc[mi][ni], 0, 0, 0);
        }
        asm volatile("s_waitcnt lgkmcnt(0)" ::: "memory");   // ds_reads done; A regs keep flying
        __builtin_amdgcn_s_barrier();
        __builtin_amdgcn_sched_barrier(0);

        if (t < 7) {
            // ---- stage(t+1): B gloads first, then pack A(t+1), then issue A(t+2)
#pragma unroll
            for (int i = 0; i < 8; ++i)
                gload16(bg + (size_t)i * 4096 + (t + 1) * 8, &Bld[i * 512 + tid]);
            uint4 u;                      // pack waits pa[cur^1] (vmcnt 8), B flies
            u.x = pack2(pa[cur ^ 1][0].x, pa[cur ^ 1][0].y);
            u.y = pack2(pa[cur ^ 1][0].z, pa[cur ^ 1][0].w);
            u.z = pack2(pa[cur ^ 1][1].x, pa[cur ^ 1][1].y);
            u.w = pack2(pa[cur ^ 1][1].z, pa[cur ^ 1][1].w);
            Ald[aslot] = u;
            if (t < 6) {                  // issue A(t+2) — newest in queue
                pa[cur][0] = *(const float4*)(aptr + (t + 2) * 64);
                pa[cur][1] = *(const float4*)(aptr + (t + 2) * 64 + 4);
                asm volatile("s_waitcnt vmcnt(2) lgkmcnt(0)" ::: "memory");  // B done, A flies
            } else {
                asm volatile("s_waitcnt vmcnt(0) lgkmcnt(0)" ::: "memory");
            }
            __builtin_amdgcn_s_barrier();
            __builtin_amdgcn_sched_barrier(0);
        }
    }

    // ---- scores: tanh + dot v, reduce across 512 n
    float vv[4], qn[4];
#pragma unroll
    for (int ni = 0; ni < 4; ++ni) {
        int n = wv * 64 + ni * 16 + l15;
        vv[ni] = vvec[n];
        qn[ni] = qc[b * HD + n];
    }
#pragma unroll
    for (int mi = 0; mi < 4; ++mi) {
#pragma unroll
        for (int r = 0; r < 4; ++r) {
            const int rowl = mi * 16 + l4 * 4 + r;   // s-row 0..63
            float s = 0.f;
#pragma unroll
            for (int ni = 0; ni < 4; ++ni)
                s += tanh_fast(acc[mi][ni][r] + qn[ni]) * vv[ni];
#pragma unroll
            for (int msk = 8; msk >= 1; msk >>= 1)
                s += __shfl_xor(s, msk);
            if (l15 == 0) red[rowl][wv] = s;
        }
    }
    __syncthreads();
    if (tid < 64) {                      // wave 0
        float t = ((red[tid][0] + red[tid][1]) + (red[tid][2] + red[tid][3]))
                + ((red[tid][4] + red[tid][5]) + (red[tid][6] + red[tid][7]));
        float p = __expf(t);             // |t| <= sum|v| ~ 20: safe
        p_lds[tid] = p;
        float l = p;
#pragma unroll
        for (int msk = 32; msk >= 1; msk >>= 1) l += __shfl_xor(l, msk);
        if (tid == 0) lP[b * NCH + c] = l;
    }
    __syncthreads();

    // ---- o-phase: wave wv owns s-rows wv*8..+7, lane owns h = lane*8..+7
    float o8[8] = {};
    const float* ebase = enc + ((size_t)(s0 + wv * 8) * 64 + b) * HD + lane * 8;
#pragma unroll
    for (int i = 0; i < 8; ++i) {
        float w = p_lds[wv * 8 + i];
        const float* ep = ebase + (size_t)i * 64 * HD;
        float4 e0 = *(const float4*)(ep);
        float4 e1 = *(const float4*)(ep + 4);
        o8[0] += w * e0.x; o8[1] += w * e0.y; o8[2] += w * e0.z; o8[3] += w * e0.w;
        o8[4] += w * e1.x; o8[5] += w * e1.y; o8[6] += w * e1.z; o8[7] += w * e1.w;
    }
    {
        float4* dst = (float4*)&opart[wv * 512 + lane * 8];
        float4 w0 = {o8[0], o8[1], o8[2], o8[3]};
        float4 w1 = {o8[4], o8[5], o8[6], o8[7]};
        dst[0] = w0; dst[1] = w1;
    }
    __syncthreads();
    float o = 0.f;
#pragma unroll
    for (int w = 0; w < 8; ++w) o += opart[w * 512 + tid];
    oP[((size_t)b * NCH + c) * HD + tid] = o;
}

// ---------------------------------------------------------------------------
// combine partials -> context; write x (emb gather + ctx) and y_bf ctx half
__global__ void combine_kernel(const float* __restrict__ oP,
                               const float* __restrict__ lP,
                               const int* __restrict__ word,
                               const float* __restrict__ emb,
                               float* __restrict__ x,
                               unsigned* __restrict__ y_bf) {
    const int b = blockIdx.x;
    const int tid = threadIdx.x;    // 512
    __shared__ float ctx_lds[512];
    float L = 0.f;
#pragma unroll 8
    for (int c = 0; c < NCH; ++c) L += lP[b * NCH + c];
    float o = 0.f;
#pragma unroll 4
    for (int c = 0; c < NCH; ++c)
        o += oP[((size_t)b * NCH + c) * HD + tid];
    float ctx = o / L;
    x[b * 1024 + HD + tid] = ctx;
    ctx_lds[tid] = ctx;
    x[b * 1024 + tid] = emb[(size_t)word[b] * HD + tid];
    __syncthreads();
    if (tid < 256)
        y_bf[b * 512 + 256 + tid] = pack2(ctx_lds[2 * tid], ctx_lds[2 * tid + 1]);
}

// ---------------------------------------------------------------------------
__global__ void gates_kernel(const float* __restrict__ x,
                             const float* __restrict__ hid,
                             const float* __restrict__ W_ih,
                             const float* __restrict__ W_hh,
                             const float* __restrict__ b_ih,
                             const float* __restrict__ b_hh,
                             float* __restrict__ gi, float* __restrict__ gh) {
    const int tid = threadIdx.x;
    const int b = tid & 63;
    const int j = blockIdx.x * 4 + (tid >> 6);
    float agi = 0.f, agh = 0.f;
    const float* xr = x + b * 1024;
    const float* wr = W_ih + (size_t)j * 1024;
    for (int k = 0; k < 1024; k += 4) {
        float4 xv = *(const float4*)(xr + k);
        float4 w4 = *(const float4*)(wr + k);
        agi += xv.x * w4.x + xv.y * w4.y + xv.z * w4.z + xv.w * w4.w;
    }
    const float* hr = hid + b * HD;
    const float* wh = W_hh + (size_t)j * HD;
    for (int k = 0; k < HD; k += 4) {
        float4 hv = *(const float4*)(hr + k);
        float4 w4 = *(const float4*)(wh + k);
        agh += hv.x * w4.x + hv.y * w4.y + hv.z * w4.z + hv.w * w4.w;
    }
    gi[b * 1536 + j] = agi + b_ih[j];
    gh[b * 1536 + j] = agh + b_hh[j];
}

__global__ void hnew_kernel(const float* __restrict__ gi,
                            const float* __restrict__ gh,
                            const float* __restrict__ hid,
                            float* __restrict__ out_h,
                            unsigned* __restrict__ y_bf) {
    const int b = blockIdx.x;
    const int h = threadIdx.x * 2;           // 256 thr
    float hn[2];
#pragma unroll
    for (int j = 0; j < 2; ++j) {
        int hh = h + j;
        float r = sigmoid_fast(gi[b * 1536 + hh] + gh[b * 1536 + hh]);
        float z = sigmoid_fast(gi[b * 1536 + 512 + hh] + gh[b * 1536 + 512 + hh]);
        float n = tanh_fast(gi[b * 1536 + 1024 + hh] + r * gh[b * 1536 + 1024 + hh]);
        hn[j] = (1.f - z) * n + z * hid[b * HD + hh];
        out_h[b * HD + hh] = hn[j];
    }
    y_bf[b * 512 + (h >> 1)] = pack2(hn[0], hn[1]);
}

// ---------------------------------------------------------------------------
// logits: BM=64, BN=64, BK=64, K=1024 (16 iters), 256 thr (4 waves), grid 500.
// W 1-deep reg prefetch; vmcnt(4) waits only the A gloads.
__global__ __launch_bounds__(256, 4) void logits_kernel(
    const unsigned short* __restrict__ y_bf,  // (64, 1024) bf16
    const float* __restrict__ out_W,          // (V, 1024)
    const float* __restrict__ out_b,
    float* __restrict__ logits)               // (64, V)
{
    __shared__ uint4 Yld[64 * 8];      // 8 KB
    __shared__ uint4 Wld[64 * 8];      // 8 KB
    const int tid = threadIdx.x;
    const int wv = tid >> 6, lane = tid & 63, l15 = lane & 15, l4 = lane >> 4;
    const int n0 = blockIdx.x * 64;

    f32x4 acc[4] = {};

    const int s1 = tid, s2 = tid + 256;
    const int r1 = s1 >> 3, g1 = (s1 & 7) ^ (r1 & 7);
    const int r2 = s2 >> 3, g2 = (s2 & 7) ^ (r2 & 7);
    const unsigned short* ya1 = y_bf + (size_t)r1 * 1024 + g1 * 8;
    const unsigned short* ya2 = y_bf + (size_t)r2 * 1024 + g2 * 8;

    const int wr = tid >> 3, wc8 = tid & 7;   // rows wr, wr+32
    const int wsl = wc8 ^ (wr & 7);
    const float* wp0 = out_W + (size_t)(n0 + wr) * 1024 + wc8 * 8;
    const float* wp1 = out_W + (size_t)(n0 + wr + 32) * 1024 + wc8 * 8;

    float4 pw[2][4];
    pw[0][0] = *(const float4*)(wp0);
    pw[0][1] = *(const float4*)(wp0 + 4);
    pw[0][2] = *(const float4*)(wp1);
    pw[0][3] = *(const float4*)(wp1 + 4);

#pragma unroll
    for (int t = 0; t < 16; ++t) {
        const int cur = t & 1;
        if (t > 0) {
            asm volatile("s_waitcnt lgkmcnt(0)" ::: "memory");
            __builtin_amdgcn_s_barrier();
            __builtin_amdgcn_sched_barrier(0);
        }
        gload16(ya1 + t * 64, &Yld[s1]);          // A first (oldest)
        gload16(ya2 + t * 64, &Yld[s2]);
        {
            uint4 u;                               // pack W(t); waits pw[cur] only
            u.x = pack2(pw[cur][0].x, pw[cur][0].y);
            u.y = pack2(pw[cur][0].z, pw[cur][0].w);
            u.z = pack2(pw[cur][1].x, pw[cur][1].y);
            u.w = pack2(pw[cur][1].z, pw[cur][1].w);
            Wld[wr * 8 + wsl] = u;
            u.x = pack2(pw[cur][2].x, pw[cur][2].y);
            u.y = pack2(pw[cur][2].z, pw[cur][2].w);
            u.z = pack2(pw[cur][3].x, pw[cur][3].y);
            u.w = pack2(pw[cur][3].z, pw[cur][3].w);
            Wld[(wr + 32) * 8 + wsl] = u;
        }
        if (t < 15) {
            const int k1 = (t + 1) * 64;
            pw[cur ^ 1][0] = *(const float4*)(wp0 + k1);
            pw[cur ^ 1][1] = *(const float4*)(wp0 + k1 + 4);
            pw[cur ^ 1][2] = *(const float4*)(wp1 + k1);
            pw[cur ^ 1][3] = *(const float4*)(wp1 + k1 + 4);
            asm volatile("s_waitcnt vmcnt(4) lgkmcnt(0)" ::: "memory");  // A done, W(t+1) flies
        } else {
            asm volatile("s_waitcnt vmcnt(0) lgkmcnt(0)" ::: "memory");
        }
        __builtin_amdgcn_s_barrier();
        __builtin_amdgcn_sched_barrier(0);

#pragma unroll
        for (int ks = 0; ks < 2; ++ks) {
            const int chunk = ks * 4 + l4;
            bf16x8 af[4], bfr;
#pragma unroll
            for (int mi = 0; mi < 4; ++mi) {
                int row = mi * 16 + l15;
                af[mi] = *(const bf16x8*)&Yld[row * 8 + (chunk ^ (row & 7))];
            }
            {
                int row = wv * 16 + l15;
                bfr = *(const bf16x8*)&Wld[row * 8 + (chunk ^ (row & 7))];
            }
#pragma unroll
            for (int mi = 0; mi < 4; ++mi)
                acc[mi] = __builtin_amdgcn_mfma_f32_16x16x32_bf16(
                    af[mi], bfr, acc[mi], 0, 0, 0);
        }
    }
#pragma unroll
    for (int mi = 0; mi < 4; ++mi) {
#pragma unroll
        for (int r = 0; r < 4; ++r) {
            const int b = mi * 16 + l4 * 4 + r;
            int n = n0 + wv * 16 + l15;
            logits[(size_t)b * VV + n] = acc[mi][r] + out_b[n];
        }
    }
}

__global__ void lsm_kernel(float* __restrict__ logits) {
    const int b = blockIdx.x;
    const int tid = threadIdx.x;  // 1024
    __shared__ float sm[1024];
    float* row = logits + (size_t)b * VV;
    float m = -1e30f;
    for (int i = tid; i < VV; i += 1024) m = fmaxf(m, row[i]);
    sm[tid] = m; __syncthreads();
    for (int o = 512; o > 0; o >>= 1) {
        if (tid < o) sm[tid] = fmaxf(sm[tid], sm[tid + o]);
        __syncthreads();
    }
    m = sm[0]; __syncthreads();
    float s = 0.f;
    for (int i = tid; i < VV; i += 1024) s += __expf(row[i] - m);
    sm[tid] = s; __syncthreads();
    for (int o = 512; o > 0; o >>= 1) {
        if (tid < o) sm[tid] += sm[tid + o];
        __syncthreads();
    }
    float lse = m + __logf(sm[0]);
    for (int i = tid; i < VV; i += 1024) row[i] -= lse;
}

// ---------------------------------------------------------------------------
extern "C" void kernel_launch(void* const* d_in, const int* in_sizes, int n_in,
                              void* d_out, int out_size, void* d_ws, size_t ws_size,
                              hipStream_t stream) {
    (void)in_sizes; (void)n_in; (void)out_size; (void)ws_size;
    const int*   word   = (const int*)d_in[0];
    const float* hid    = (const float*)d_in[1];
    const float* enc    = (const float*)d_in[2];
    const float* emb    = (const float*)d_in[3];
    const float* attn_W = (const float*)d_in[4];
    const float* attn_b = (const float*)d_in[5];
    const float* v      = (const float*)d_in[6];
    const float* W_ih   = (const float*)d_in[7];
    const float* W_hh   = (const float*)d_in[8];
    const float* b_ih   = (const float*)d_in[9];
    const float* b_hh   = (const float*)d_in[10];
    const float* out_W  = (const float*)d_in[11];
    const float* out_b  = (const float*)d_in[12];

    float* out    = (float*)d_out;
    float* logits = out;                         // (B, V)
    float* out_h  = out + (size_t)BB * VV;       // (B, H)

    char* ws0 = (char*)d_ws;
    size_t off = 0;
    float* qc      = (float*)(ws0 + off);    off += 64 * 512 * 4;
    uint4* WeB4    = (uint4*)(ws0 + off);    off += 512 * 512 * 2;
    float* oP      = (float*)(ws0 + off);    off += (size_t)BB * NCH * HD * 4;
    float* lP      = (float*)(ws0 + off);    off += BB * NCH * 4;
    float* x       = (float*)(ws0 + off);    off += 64 * 1024 * 4;
    unsigned* y_bf = (unsigned*)(ws0 + off); off += 64 * 1024 * 2;
    float* gi      = (float*)(ws0 + off);    off += 64 * 1536 * 4;
    float* gh      = (float*)(ws0 + off);    off += 64 * 1536 * 4;

    prep_kernel<<<128, 256, 0, stream>>>(hid, attn_W, attn_b, qc, WeB4);
    fattn_kernel<<<BB * NCH, 512, 0, stream>>>(enc, WeB4, qc, v, oP, lP);
    combine_kernel<<<BB, 512, 0, stream>>>(oP, lP, word, emb, x, y_bf);
    gates_kernel<<<384, 256, 0, stream>>>(x, hid, W_ih, W_hh, b_ih, b_hh, gi, gh);
    hnew_kernel<<<BB, 256, 0, stream>>>(gi, gh, hid, out_h, y_bf);
    logits_kernel<<<VV / 64, 256, 0, stream>>>((const unsigned short*)y_bf, out_W, out_b, logits);
    lsm_kernel<<<BB, 1024, 0, stream>>>(logits);
}